// Round 1
// baseline (389.165 us; speedup 1.0000x reference)
//
#include <hip/hip_runtime.h>

typedef unsigned short u16;
typedef __bf16 bf16x8 __attribute__((ext_vector_type(8)));
typedef float f32x4 __attribute__((ext_vector_type(4)));

#define S_LEN  2048
#define NHEADS 16
#define NKVH   4
#define HDIM   128
#define BB     2
#define MROWS  4096   // B*S
#define QKV_N  3072   // NH*HD + 2*NKV*HD
#define HID    2048

__device__ __forceinline__ u16 f2b(float f) {
  union { float f; unsigned u; } x; x.f = f;
  unsigned r = x.u + 0x7fffu + ((x.u >> 16) & 1u);
  return (u16)(r >> 16);
}
__device__ __forceinline__ float b2f(u16 v) {
  union { unsigned u; float f; } x; x.u = ((unsigned)v) << 16;
  return x.f;
}
__device__ __forceinline__ void gload_lds16(const u16* g, u16* l) {
  __builtin_amdgcn_global_load_lds((__attribute__((address_space(1))) void*)g,
                                   (__attribute__((address_space(3))) void*)l,
                                   16, 0, 0);
}

// fp32 -> bf16 conversion, 4 elements/thread
__global__ void k_f2b4(const float* __restrict__ in, u16* __restrict__ out, int n4) {
  int i = blockIdx.x * blockDim.x + threadIdx.x;
  if (i >= n4) return;
  float4 v = ((const float4*)in)[i];
  ushort4 o;
  o.x = f2b(v.x); o.y = f2b(v.y); o.z = f2b(v.z); o.w = f2b(v.w);
  ((ushort4*)out)[i] = o;
}

// RoPE cos/sin table: cs[s][j][2] = {cos, sin} of s * theta^(-j/64)
__global__ void k_cs(float* __restrict__ cs) {
  int s = blockIdx.x, j = threadIdx.x;  // 2048 x 64
  float inv = expf(-(float)j * 0.14391156831212787f);  // ln(10000)/64
  float ang = (float)s * inv;
  float c, sn;
  sincosf(ang, &sn, &c);
  cs[(s * 64 + j) * 2 + 0] = c;
  cs[(s * 64 + j) * 2 + 1] = sn;
}

// C[M][N] = A[M][K] * B[N][K]^T, bf16 in, bf16 or fp32 out. 128x128 tile, BK=32.
template <int OUT_BF16>
__global__ __launch_bounds__(256) void k_gemm_bt(
    const u16* __restrict__ A, const u16* __restrict__ Bm, void* __restrict__ Cv,
    int M, int N, int K)
{
  __shared__ u16 Al[128 * 32];
  __shared__ u16 Bl[128 * 32];
  const int tid = threadIdx.x;
  const int wave = tid >> 6, lane = tid & 63;
  const int l15 = lane & 15, l4 = lane >> 4;
  const int wr = wave >> 1, wc = wave & 1;
  const int row0 = blockIdx.y * 128, col0 = blockIdx.x * 128;

  f32x4 zero = {0.f, 0.f, 0.f, 0.f};
  f32x4 acc[4][4];
#pragma unroll
  for (int m = 0; m < 4; ++m)
#pragma unroll
    for (int n = 0; n < 4; ++n) acc[m][n] = zero;

  const int e0 = lane * 8;
  for (int kb = 0; kb < K; kb += 32) {
#pragma unroll
    for (int it = 0; it < 2; ++it) {
      const int chunk = it * 4 + wave;
      const int e = chunk * 512 + e0;        // bf16 element index in tile
      const int r = e >> 5, c = e & 31;
      gload_lds16(A + (size_t)(row0 + r) * K + kb + c, Al + chunk * 512);
      gload_lds16(Bm + (size_t)(col0 + r) * K + kb + c, Bl + chunk * 512);
    }
    __syncthreads();
    bf16x8 af[4], bfv[4];
#pragma unroll
    for (int m = 0; m < 4; ++m)
      af[m] = *(const bf16x8*)(Al + (wr * 64 + m * 16 + l15) * 32 + l4 * 8);
#pragma unroll
    for (int n = 0; n < 4; ++n)
      bfv[n] = *(const bf16x8*)(Bl + (wc * 64 + n * 16 + l15) * 32 + l4 * 8);
#pragma unroll
    for (int m = 0; m < 4; ++m)
#pragma unroll
      for (int n = 0; n < 4; ++n)
        acc[m][n] = __builtin_amdgcn_mfma_f32_16x16x32_bf16(af[m], bfv[n], acc[m][n], 0, 0, 0);
    __syncthreads();
  }
  // epilogue: D layout col=lane&15, row=(lane>>4)*4+j  [m89/m91 verified]
#pragma unroll
  for (int m = 0; m < 4; ++m) {
    const int r = row0 + wr * 64 + m * 16 + l4 * 4;
#pragma unroll
    for (int n = 0; n < 4; ++n) {
      const int c = col0 + wc * 64 + n * 16 + l15;
#pragma unroll
      for (int j = 0; j < 4; ++j) {
        const float v = acc[m][n][j];
        if (OUT_BF16) ((u16*)Cv)[(size_t)(r + j) * N + c] = f2b(v);
        else          ((float*)Cv)[(size_t)(r + j) * N + c] = v;
      }
    }
  }
}

// RoPE + layout: qkv[row][3072] -> Qr[b][h][s][d], Kr[b][kvh][s][d], Vt[b][kvh][d][s]
__global__ __launch_bounds__(256) void k_rope(
    const u16* __restrict__ qkv, const float* __restrict__ cs,
    u16* __restrict__ Qr, u16* __restrict__ Kr, u16* __restrict__ Vt)
{
  const int row = blockIdx.x;           // b*S + s
  const int b = row >> 11, s = row & 2047;
  const int t = threadIdx.x;            // 256
  const u16* src = qkv + (size_t)row * QKV_N;
#pragma unroll
  for (int p = t; p < 1024; p += 256) {  // Q: 16 heads x 64 pairs
    const int h = p >> 6, j = p & 63;
    const float c = cs[(s * 64 + j) * 2], sn = cs[(s * 64 + j) * 2 + 1];
    const float x0 = b2f(src[h * 128 + j]);
    const float x1 = b2f(src[h * 128 + 64 + j]);
    const size_t base = ((size_t)(b * NHEADS + h) * S_LEN + s) * HDIM;
    Qr[base + j]      = f2b(x0 * c - x1 * sn);
    Qr[base + 64 + j] = f2b(x1 * c + x0 * sn);
  }
  {  // K: 4 heads x 64 pairs == 256 threads exactly
    const int h = t >> 6, j = t & 63;
    const float c = cs[(s * 64 + j) * 2], sn = cs[(s * 64 + j) * 2 + 1];
    const float x0 = b2f(src[2048 + h * 128 + j]);
    const float x1 = b2f(src[2048 + h * 128 + 64 + j]);
    const size_t base = ((size_t)(b * NKVH + h) * S_LEN + s) * HDIM;
    Kr[base + j]      = f2b(x0 * c - x1 * sn);
    Kr[base + 64 + j] = f2b(x1 * c + x0 * sn);
  }
#pragma unroll
  for (int p = t; p < 512; p += 256) {   // V transpose store
    const int h = p >> 7, d = p & 127;
    Vt[((size_t)(b * NKVH + h) * HDIM + d) * S_LEN + s] = src[2560 + p];
  }
}

// Flash attention: 64 q-rows/block, 4 waves x 16 rows, KT=32 KV tiles, causal.
__global__ __launch_bounds__(256) void k_attn(
    const u16* __restrict__ Q, const u16* __restrict__ Kr,
    const u16* __restrict__ Vt, u16* __restrict__ Out)
{
  __shared__ u16 Kl[32 * 128];     // [kv][d], XOR-swizzled (row&7)<<4
  __shared__ u16 Vl[128 * 32];     // [d][kv], XOR-swizzled ((d>>3)&3)<<4
  __shared__ u16 Pl[4][16 * 48];   // per-wave P, stride 48 (96B, 16B-aligned)
  const int tid = threadIdx.x;
  const int wave = tid >> 6, lane = tid & 63;
  const int l15 = lane & 15, l4 = lane >> 4;
  const int qb = blockIdx.x * 64;
  const int bh = blockIdx.y;              // b*NH + h
  const int b = bh >> 4, h = bh & 15;
  const int kvh = h >> 2;

  const u16* Qg = Q + ((size_t)bh * S_LEN + qb + wave * 16) * HDIM;
  const u16* Kg = Kr + (size_t)(b * NKVH + kvh) * S_LEN * HDIM;
  const u16* Vg = Vt + (size_t)(b * NKVH + kvh) * HDIM * S_LEN;

  bf16x8 qf[4];
#pragma unroll
  for (int kc = 0; kc < 4; ++kc)
    qf[kc] = *(const bf16x8*)(Qg + l15 * HDIM + kc * 32 + l4 * 8);

  f32x4 zero = {0.f, 0.f, 0.f, 0.f};
  f32x4 oacc[8];
#pragma unroll
  for (int i = 0; i < 8; ++i) oacc[i] = zero;
  float m_r[4], l_r[4];
#pragma unroll
  for (int j = 0; j < 4; ++j) { m_r[j] = -1e30f; l_r[j] = 0.f; }

  const float scale = 0.08838834764831845f;  // 1/sqrt(128)
  const int qw0 = qb + wave * 16;
  const int kv_end = qb + 64;
  const int Lb = lane * 16;

  for (int kt = 0; kt < kv_end; kt += 32) {
    // stage K [32][128] and V [128][32], both via global_load_lds with
    // pre-swizzled SOURCE (linear LDS dest) — rule 21 both-sides swizzle
#pragma unroll
    for (int it = 0; it < 2; ++it) {
      const int chunk = it * 4 + wave;
      const int L = chunk * 1024 + Lb;                  // byte in tile
      const int LsK = L ^ (((L >> 8) & 7) << 4);
      gload_lds16(Kg + (size_t)kt * HDIM + (LsK >> 1), Kl + chunk * 512);
      const int LsV = L ^ (((L >> 9) & 3) << 4);
      gload_lds16(Vg + (size_t)(LsV >> 6) * S_LEN + kt + ((LsV & 63) >> 1),
                  Vl + chunk * 512);
    }
    __syncthreads();

    if (kt <= qw0 + 15) {  // wave has at least one unmasked column in tile
      // S = Q K^T : two 16-col subtiles
      f32x4 sfr[2];
#pragma unroll
      for (int n = 0; n < 2; ++n) {
        f32x4 a = zero;
        const int row = n * 16 + l15;
#pragma unroll
        for (int kc = 0; kc < 4; ++kc) {
          const int ab = (row * 256 + kc * 64 + l4 * 16) ^ ((row & 7) << 4);
          bf16x8 kf = *(const bf16x8*)((const char*)Kl + ab);
          a = __builtin_amdgcn_mfma_f32_16x16x32_bf16(qf[kc], kf, a, 0, 0, 0);
        }
        sfr[n] = a;
      }
      // scale + causal mask
      float sv[2][4], mx[4];
#pragma unroll
      for (int j = 0; j < 4; ++j) {
        const int qg = qw0 + l4 * 4 + j;
#pragma unroll
        for (int n = 0; n < 2; ++n) {
          float s = sfr[n][j] * scale;
          const int kg = kt + n * 16 + l15;
          sv[n][j] = (kg <= qg) ? s : -1e30f;
        }
        mx[j] = fmaxf(sv[0][j], sv[1][j]);
      }
      // row max across the 16 lanes of each quarter-wave
#pragma unroll
      for (int off = 1; off < 16; off <<= 1)
#pragma unroll
        for (int j = 0; j < 4; ++j)
          mx[j] = fmaxf(mx[j], __shfl_xor(mx[j], off, 64));
      float sc[4], rs[4];
#pragma unroll
      for (int j = 0; j < 4; ++j) {
        const float mn = fmaxf(m_r[j], mx[j]);
        sc[j] = __expf(m_r[j] - mn);
        m_r[j] = mn;
        rs[j] = 0.f;
      }
      float ps[2][4];
#pragma unroll
      for (int n = 0; n < 2; ++n)
#pragma unroll
        for (int j = 0; j < 4; ++j) {
          ps[n][j] = __expf(sv[n][j] - m_r[j]);
          rs[j] += ps[n][j];
        }
#pragma unroll
      for (int off = 1; off < 16; off <<= 1)
#pragma unroll
        for (int j = 0; j < 4; ++j)
          rs[j] += __shfl_xor(rs[j], off, 64);
#pragma unroll
      for (int j = 0; j < 4; ++j) l_r[j] = l_r[j] * sc[j] + rs[j];
#pragma unroll
      for (int i = 0; i < 8; ++i)
#pragma unroll
        for (int j = 0; j < 4; ++j) oacc[i][j] *= sc[j];
      // P -> LDS (bf16), D-layout row=(l4*4+j), col=(n*16+l15)
#pragma unroll
      for (int n = 0; n < 2; ++n)
#pragma unroll
        for (int j = 0; j < 4; ++j)
          Pl[wave][(l4 * 4 + j) * 48 + n * 16 + l15] = f2b(ps[n][j]);
      // PV: A = P[16q x 32k], B = V[32k x 16d] from d-major Vl
      bf16x8 pf = *(const bf16x8*)(&Pl[wave][l15 * 48 + l4 * 8]);
#pragma unroll
      for (int nd = 0; nd < 8; ++nd) {
        const int d = nd * 16 + l15;
        const int ab = (d * 64 + l4 * 16) ^ (((d >> 3) & 3) << 4);
        bf16x8 vf = *(const bf16x8*)((const char*)Vl + ab);
        oacc[nd] = __builtin_amdgcn_mfma_f32_16x16x32_bf16(pf, vf, oacc[nd], 0, 0, 0);
      }
    }
    __syncthreads();
  }

  float il[4];
#pragma unroll
  for (int j = 0; j < 4; ++j) il[j] = 1.f / l_r[j];
  const size_t obase = ((size_t)b * S_LEN + qw0 + l4 * 4) * HID + h * HDIM;
#pragma unroll
  for (int nd = 0; nd < 8; ++nd)
#pragma unroll
    for (int j = 0; j < 4; ++j)
      Out[obase + (size_t)j * HID + nd * 16 + l15] = f2b(oacc[nd][j] * il[j]);
}

extern "C" void kernel_launch(void* const* d_in, const int* in_sizes, int n_in,
                              void* d_out, int out_size, void* d_ws, size_t ws_size,
                              hipStream_t stream)
{
  const float* x  = (const float*)d_in[0];
  // d_in[1] = attention_mask (pure causal -> computed in-kernel)
  const float* Wq = (const float*)d_in[2];
  const float* Wk = (const float*)d_in[3];
  const float* Wv = (const float*)d_in[4];
  const float* Wo = (const float*)d_in[5];
  float* out = (float*)d_out;

  u16* xb    = (u16*)d_ws;                              // [4096][2048]
  u16* Wqkvb = xb    + (size_t)MROWS * HID;             // [3072][2048]
  u16* Wob   = Wqkvb + (size_t)QKV_N * HID;             // [2048][2048]
  u16* qkv   = Wob   + (size_t)HID * HID;               // [4096][3072]
  u16* Qr    = qkv   + (size_t)MROWS * QKV_N;           // [2][16][2048][128]
  u16* Kr    = Qr    + (size_t)BB * NHEADS * S_LEN * HDIM; // [2][4][2048][128]
  u16* Vt    = Kr    + (size_t)BB * NKVH * S_LEN * HDIM;   // [2][4][128][2048]
  u16* attn  = Vt    + (size_t)BB * NKVH * S_LEN * HDIM;   // [4096][2048]
  float* cs  = (float*)(attn + (size_t)MROWS * HID);    // [2048][64][2]

  k_f2b4<<<dim3((MROWS * HID / 4) / 256), 256, 0, stream>>>(x, xb, MROWS * HID / 4);
  k_f2b4<<<dim3((HID * HID / 4) / 256), 256, 0, stream>>>(Wq, Wqkvb, HID * HID / 4);
  k_f2b4<<<dim3((512 * HID / 4) / 256), 256, 0, stream>>>(Wk, Wqkvb + (size_t)2048 * HID, 512 * HID / 4);
  k_f2b4<<<dim3((512 * HID / 4) / 256), 256, 0, stream>>>(Wv, Wqkvb + (size_t)2560 * HID, 512 * HID / 4);
  k_f2b4<<<dim3((HID * HID / 4) / 256), 256, 0, stream>>>(Wo, Wob, HID * HID / 4);
  k_cs<<<dim3(S_LEN), dim3(64), 0, stream>>>(cs);
  k_gemm_bt<1><<<dim3(QKV_N / 128, MROWS / 128), 256, 0, stream>>>(xb, Wqkvb, qkv, MROWS, QKV_N, HID);
  k_rope<<<dim3(MROWS), 256, 0, stream>>>(qkv, cs, Qr, Kr, Vt);
  k_attn<<<dim3(S_LEN / 64, BB * NHEADS), 256, 0, stream>>>(Qr, Kr, Vt, attn);
  k_gemm_bt<0><<<dim3(HID / 128, MROWS / 128), 256, 0, stream>>>(attn, Wob, out, MROWS, HID, HID);
}

// Round 2
// 328.890 us; speedup vs baseline: 1.1833x; 1.1833x over previous
//
#include <hip/hip_runtime.h>

typedef unsigned short u16;
typedef __bf16 bf16x8 __attribute__((ext_vector_type(8)));
typedef float f32x4 __attribute__((ext_vector_type(4)));

#define S_LEN  2048
#define NHEADS 16
#define NKVH   4
#define HDIM   128
#define BB     2
#define MROWS  4096   // B*S
#define QKV_N  3072   // NH*HD + 2*NKV*HD
#define HID    2048

__device__ __forceinline__ u16 f2b(float f) {
  union { float f; unsigned u; } x; x.f = f;
  unsigned r = x.u + 0x7fffu + ((x.u >> 16) & 1u);
  return (u16)(r >> 16);
}
__device__ __forceinline__ u16 f2b_fast(float f) {  // round-half-up, 2 ops
  union { float f; unsigned u; } x; x.f = f;
  return (u16)((x.u + 0x8000u) >> 16);
}
__device__ __forceinline__ float b2f(u16 v) {
  union { unsigned u; float f; } x; x.u = ((unsigned)v) << 16;
  return x.f;
}
__device__ __forceinline__ void gload_lds16(const u16* g, u16* l) {
  __builtin_amdgcn_global_load_lds((__attribute__((address_space(1))) void*)g,
                                   (__attribute__((address_space(3))) void*)l,
                                   16, 0, 0);
}

// fp32 -> bf16 conversion, 4 elements/thread
__global__ void k_f2b4(const float* __restrict__ in, u16* __restrict__ out, int n4) {
  int i = blockIdx.x * blockDim.x + threadIdx.x;
  if (i >= n4) return;
  float4 v = ((const float4*)in)[i];
  ushort4 o;
  o.x = f2b(v.x); o.y = f2b(v.y); o.z = f2b(v.z); o.w = f2b(v.w);
  ((ushort4*)out)[i] = o;
}

// RoPE cos/sin table: cs[s][j][2] = {cos, sin} of s * theta^(-j/64)
__global__ void k_cs(float* __restrict__ cs) {
  int s = blockIdx.x, j = threadIdx.x;  // 2048 x 64
  float inv = expf(-(float)j * 0.14391156831212787f);  // ln(10000)/64
  float ang = (float)s * inv;
  float c, sn;
  sincosf(ang, &sn, &c);
  cs[(s * 64 + j) * 2 + 0] = c;
  cs[(s * 64 + j) * 2 + 1] = sn;
}

// C[M][N] = A[M][K] * B[N][K]^T, bf16 in, bf16 or fp32 out. 128x128 tile, BK=32.
template <int OUT_BF16>
__global__ __launch_bounds__(256) void k_gemm_bt(
    const u16* __restrict__ A, const u16* __restrict__ Bm, void* __restrict__ Cv,
    int M, int N, int K)
{
  __shared__ u16 Al[128 * 32];
  __shared__ u16 Bl[128 * 32];
  const int tid = threadIdx.x;
  const int wave = tid >> 6, lane = tid & 63;
  const int l15 = lane & 15, l4 = lane >> 4;
  const int wr = wave >> 1, wc = wave & 1;
  const int row0 = blockIdx.y * 128, col0 = blockIdx.x * 128;

  f32x4 zero = {0.f, 0.f, 0.f, 0.f};
  f32x4 acc[4][4];
#pragma unroll
  for (int m = 0; m < 4; ++m)
#pragma unroll
    for (int n = 0; n < 4; ++n) acc[m][n] = zero;

  const int e0 = lane * 8;
  for (int kb = 0; kb < K; kb += 32) {
#pragma unroll
    for (int it = 0; it < 2; ++it) {
      const int chunk = it * 4 + wave;
      const int e = chunk * 512 + e0;        // bf16 element index in tile
      const int r = e >> 5, c = e & 31;
      gload_lds16(A + (size_t)(row0 + r) * K + kb + c, Al + chunk * 512);
      gload_lds16(Bm + (size_t)(col0 + r) * K + kb + c, Bl + chunk * 512);
    }
    __syncthreads();
    bf16x8 af[4], bfv[4];
#pragma unroll
    for (int m = 0; m < 4; ++m)
      af[m] = *(const bf16x8*)(Al + (wr * 64 + m * 16 + l15) * 32 + l4 * 8);
#pragma unroll
    for (int n = 0; n < 4; ++n)
      bfv[n] = *(const bf16x8*)(Bl + (wc * 64 + n * 16 + l15) * 32 + l4 * 8);
#pragma unroll
    for (int m = 0; m < 4; ++m)
#pragma unroll
      for (int n = 0; n < 4; ++n)
        acc[m][n] = __builtin_amdgcn_mfma_f32_16x16x32_bf16(af[m], bfv[n], acc[m][n], 0, 0, 0);
    __syncthreads();
  }
  // epilogue: D layout col=lane&15, row=(lane>>4)*4+j  [m89/m91 verified]
#pragma unroll
  for (int m = 0; m < 4; ++m) {
    const int r = row0 + wr * 64 + m * 16 + l4 * 4;
#pragma unroll
    for (int n = 0; n < 4; ++n) {
      const int c = col0 + wc * 64 + n * 16 + l15;
#pragma unroll
      for (int j = 0; j < 4; ++j) {
        const float v = acc[m][n][j];
        if (OUT_BF16) ((u16*)Cv)[(size_t)(r + j) * N + c] = f2b(v);
        else          ((float*)Cv)[(size_t)(r + j) * N + c] = v;
      }
    }
  }
}

// RoPE + layout: qkv[row][3072] -> Qr[b][h][s][d], Kr[b][kvh][s][d], Vt[b][kvh][d][s]
__global__ __launch_bounds__(256) void k_rope(
    const u16* __restrict__ qkv, const float* __restrict__ cs,
    u16* __restrict__ Qr, u16* __restrict__ Kr, u16* __restrict__ Vt)
{
  const int row = blockIdx.x;           // b*S + s
  const int b = row >> 11, s = row & 2047;
  const int t = threadIdx.x;            // 256
  const u16* src = qkv + (size_t)row * QKV_N;
#pragma unroll
  for (int p = t; p < 1024; p += 256) {  // Q: 16 heads x 64 pairs
    const int h = p >> 6, j = p & 63;
    const float c = cs[(s * 64 + j) * 2], sn = cs[(s * 64 + j) * 2 + 1];
    const float x0 = b2f(src[h * 128 + j]);
    const float x1 = b2f(src[h * 128 + 64 + j]);
    const size_t base = ((size_t)(b * NHEADS + h) * S_LEN + s) * HDIM;
    Qr[base + j]      = f2b(x0 * c - x1 * sn);
    Qr[base + 64 + j] = f2b(x1 * c + x0 * sn);
  }
  {  // K: 4 heads x 64 pairs == 256 threads exactly
    const int h = t >> 6, j = t & 63;
    const float c = cs[(s * 64 + j) * 2], sn = cs[(s * 64 + j) * 2 + 1];
    const float x0 = b2f(src[2048 + h * 128 + j]);
    const float x1 = b2f(src[2048 + h * 128 + 64 + j]);
    const size_t base = ((size_t)(b * NKVH + h) * S_LEN + s) * HDIM;
    Kr[base + j]      = f2b(x0 * c - x1 * sn);
    Kr[base + 64 + j] = f2b(x1 * c + x0 * sn);
  }
#pragma unroll
  for (int p = t; p < 512; p += 256) {   // V transpose store
    const int h = p >> 7, d = p & 127;
    Vt[((size_t)(b * NKVH + h) * HDIM + d) * S_LEN + s] = src[2560 + p];
  }
}

// Flash attention v2: 128 q-rows/block, 4 waves x 32 rows, KV tiles of 64,
// heavy-first block order, log2-domain softmax, T13 defer-max.
__global__ __launch_bounds__(256, 2) void k_attn(
    const u16* __restrict__ Q, const u16* __restrict__ Kr,
    const u16* __restrict__ Vt, u16* __restrict__ Out)
{
  __shared__ u16 Kl[64 * 128];     // [kv][d], XOR swizzle ^((kv&7)<<4) on byte addr
  __shared__ u16 Vl[128 * 64];     // [d][kv], XOR swizzle ^((d&7)<<4)
  __shared__ u16 Pl[4][32 * 72];   // per-wave P[32 q][64 k], stride 72 u16 (144B, 16B-mult)
  const int tid = threadIdx.x;
  const int wave = tid >> 6, lane = tid & 63;
  const int l15 = lane & 15, l4 = lane >> 4;
  const int qt = 15 - blockIdx.x;         // heavy blocks dispatch first (LPT)
  const int qb = qt * 128;
  const int bh = blockIdx.y;              // b*NH + h
  const int b = bh >> 4, h = bh & 15;
  const int kvh = h >> 2;
  const int qw0 = qb + wave * 32;

  const u16* Qg = Q + ((size_t)bh * S_LEN + qw0) * HDIM;
  const u16* Kg = Kr + (size_t)(b * NKVH + kvh) * S_LEN * HDIM;
  const u16* Vg = Vt + (size_t)(b * NKVH + kvh) * HDIM * S_LEN;

  bf16x8 qf[2][4];
#pragma unroll
  for (int m = 0; m < 2; ++m)
#pragma unroll
    for (int kc = 0; kc < 4; ++kc)
      qf[m][kc] = *(const bf16x8*)(Qg + (m * 16 + l15) * HDIM + kc * 32 + l4 * 8);

  f32x4 zero = {0.f, 0.f, 0.f, 0.f};
  f32x4 oacc[2][8];
#pragma unroll
  for (int m = 0; m < 2; ++m)
#pragma unroll
    for (int i = 0; i < 8; ++i) oacc[m][i] = zero;
  float m_r[2][4], l_r[2][4];
#pragma unroll
  for (int m = 0; m < 2; ++m)
#pragma unroll
    for (int j = 0; j < 4; ++j) { m_r[m][j] = -1e30f; l_r[m][j] = 0.f; }

  const float S2 = 0.08838834764831845f * 1.4426950408889634f;  // scale * log2(e)
  const int nt = (qb + 128) / 64;         // = 2*(qt+1) KV tiles
  const int Lb = lane * 16;

  for (int t = 0; t < nt; ++t) {
    const int kt = t * 64;
    // ---- cooperative stage: K [64][128] + V [128][64], pre-swizzled source ----
#pragma unroll
    for (int it = 0; it < 4; ++it) {
      const int c = it * 4 + wave;
      const int L = c * 1024 + Lb;                    // linear byte in tile
      { const int r = L >> 8;                         // K: 256B per kv-row
        const int w2 = (L & 255) ^ ((r & 7) << 4);
        gload_lds16(Kg + (size_t)(kt + r) * HDIM + (w2 >> 1), Kl + c * 512); }
      { const int d = L >> 7;                         // V: 128B per d-row
        const int w2 = (L & 127) ^ ((d & 7) << 4);
        gload_lds16(Vg + (size_t)d * S_LEN + kt + (w2 >> 1), Vl + c * 512); }
    }
    __syncthreads();

    if (kt <= qw0 + 31) {
      // ---- S = Q K^T : [32 q][64 k] ----
      f32x4 s[2][4];
#pragma unroll
      for (int m = 0; m < 2; ++m)
#pragma unroll
        for (int n = 0; n < 4; ++n) s[m][n] = zero;
#pragma unroll
      for (int n = 0; n < 4; ++n) {
        const int row = n * 16 + l15;
#pragma unroll
        for (int kc = 0; kc < 4; ++kc) {
          const int ab = (row * 256 + kc * 64 + l4 * 16) ^ ((row & 7) << 4);
          bf16x8 kf = *(const bf16x8*)((const char*)Kl + ab);
#pragma unroll
          for (int m = 0; m < 2; ++m)
            s[m][n] = __builtin_amdgcn_mfma_f32_16x16x32_bf16(qf[m][kc], kf, s[m][n], 0, 0, 0);
        }
      }
      // ---- scale to log2 domain + causal mask + row max ----
      const bool domask = (kt + 63 > qw0);
      float sv[2][4][4], mx[2][4];
#pragma unroll
      for (int m = 0; m < 2; ++m)
#pragma unroll
        for (int j = 0; j < 4; ++j) {
          const int qg = qw0 + m * 16 + l4 * 4 + j;
#pragma unroll
          for (int n = 0; n < 4; ++n) {
            float x = s[m][n][j] * S2;
            if (domask && (kt + n * 16 + l15 > qg)) x = -1e30f;
            sv[m][n][j] = x;
          }
          mx[m][j] = fmaxf(fmaxf(sv[m][0][j], sv[m][1][j]),
                           fmaxf(sv[m][2][j], sv[m][3][j]));
        }
#pragma unroll
      for (int off = 1; off < 16; off <<= 1)
#pragma unroll
        for (int m = 0; m < 2; ++m)
#pragma unroll
          for (int j = 0; j < 4; ++j)
            mx[m][j] = fmaxf(mx[m][j], __shfl_xor(mx[m][j], off, 64));
      // ---- T13 defer-max: skip O-rescale when max growth <= 8/ln2 ----
      bool ok = true;
#pragma unroll
      for (int m = 0; m < 2; ++m)
#pragma unroll
        for (int j = 0; j < 4; ++j)
          ok = ok && (mx[m][j] <= m_r[m][j] + 11.5416f);
      float mu[2][4];
      if (__all(ok)) {
#pragma unroll
        for (int m = 0; m < 2; ++m)
#pragma unroll
          for (int j = 0; j < 4; ++j) mu[m][j] = m_r[m][j];
      } else {
        float sc[2][4];
#pragma unroll
        for (int m = 0; m < 2; ++m)
#pragma unroll
          for (int j = 0; j < 4; ++j) {
            const float mn = fmaxf(m_r[m][j], mx[m][j]);
            sc[m][j] = exp2f(m_r[m][j] - mn);
            m_r[m][j] = mn; mu[m][j] = mn;
            l_r[m][j] *= sc[m][j];
          }
#pragma unroll
        for (int m = 0; m < 2; ++m)
#pragma unroll
          for (int nd = 0; nd < 8; ++nd)
#pragma unroll
            for (int j = 0; j < 4; ++j) oacc[m][nd][j] *= sc[m][j];
      }
      // ---- P = exp2(sv - mu), row-sum, write P to LDS ----
      float rs[2][4];
#pragma unroll
      for (int m = 0; m < 2; ++m)
#pragma unroll
        for (int j = 0; j < 4; ++j) rs[m][j] = 0.f;
#pragma unroll
      for (int m = 0; m < 2; ++m)
#pragma unroll
        for (int n = 0; n < 4; ++n)
#pragma unroll
          for (int j = 0; j < 4; ++j) {
            const float p = exp2f(sv[m][n][j] - mu[m][j]);
            rs[m][j] += p;
            Pl[wave][(m * 16 + l4 * 4 + j) * 72 + n * 16 + l15] = f2b_fast(p);
          }
#pragma unroll
      for (int off = 1; off < 16; off <<= 1)
#pragma unroll
        for (int m = 0; m < 2; ++m)
#pragma unroll
          for (int j = 0; j < 4; ++j)
            rs[m][j] += __shfl_xor(rs[m][j], off, 64);
#pragma unroll
      for (int m = 0; m < 2; ++m)
#pragma unroll
        for (int j = 0; j < 4; ++j) l_r[m][j] += rs[m][j];
      // ---- O += P V : A=P[32q x 64k], B=V^T frags from d-major Vl ----
#pragma unroll
      for (int kc2 = 0; kc2 < 2; ++kc2) {
        bf16x8 pf[2];
#pragma unroll
        for (int m = 0; m < 2; ++m)
          pf[m] = *(const bf16x8*)(&Pl[wave][(m * 16 + l15) * 72 + kc2 * 32 + l4 * 8]);
#pragma unroll
        for (int nd = 0; nd < 8; ++nd) {
          const int d = nd * 16 + l15;
          const int ab = (d * 128 + kc2 * 64 + l4 * 16) ^ ((d & 7) << 4);
          bf16x8 vf = *(const bf16x8*)((const char*)Vl + ab);
#pragma unroll
          for (int m = 0; m < 2; ++m)
            oacc[m][nd] = __builtin_amdgcn_mfma_f32_16x16x32_bf16(pf[m], vf, oacc[m][nd], 0, 0, 0);
        }
      }
    }
    __syncthreads();
  }

  // ---- epilogue ----
#pragma unroll
  for (int m = 0; m < 2; ++m) {
    float il[4];
#pragma unroll
    for (int j = 0; j < 4; ++j) il[j] = 1.f / l_r[m][j];
    const size_t obase = ((size_t)b * S_LEN + qw0 + m * 16 + l4 * 4) * HID + h * HDIM;
#pragma unroll
    for (int nd = 0; nd < 8; ++nd)
#pragma unroll
      for (int j = 0; j < 4; ++j)
        Out[obase + (size_t)j * HID + nd * 16 + l15] = f2b(oacc[m][nd][j] * il[j]);
  }
}

extern "C" void kernel_launch(void* const* d_in, const int* in_sizes, int n_in,
                              void* d_out, int out_size, void* d_ws, size_t ws_size,
                              hipStream_t stream)
{
  const float* x  = (const float*)d_in[0];
  // d_in[1] = attention_mask (pure causal -> computed in-kernel)
  const float* Wq = (const float*)d_in[2];
  const float* Wk = (const float*)d_in[3];
  const float* Wv = (const float*)d_in[4];
  const float* Wo = (const float*)d_in[5];
  float* out = (float*)d_out;

  u16* xb    = (u16*)d_ws;                              // [4096][2048]
  u16* Wqkvb = xb    + (size_t)MROWS * HID;             // [3072][2048]
  u16* Wob   = Wqkvb + (size_t)QKV_N * HID;             // [2048][2048]
  u16* qkv   = Wob   + (size_t)HID * HID;               // [4096][3072]
  u16* Qr    = qkv   + (size_t)MROWS * QKV_N;           // [2][16][2048][128]
  u16* Kr    = Qr    + (size_t)BB * NHEADS * S_LEN * HDIM; // [2][4][2048][128]
  u16* Vt    = Kr    + (size_t)BB * NKVH * S_LEN * HDIM;   // [2][4][128][2048]
  u16* attn  = Vt    + (size_t)BB * NKVH * S_LEN * HDIM;   // [4096][2048]
  float* cs  = (float*)(attn + (size_t)MROWS * HID);    // [2048][64][2]

  k_f2b4<<<dim3((MROWS * HID / 4) / 256), 256, 0, stream>>>(x, xb, MROWS * HID / 4);
  k_f2b4<<<dim3((HID * HID / 4) / 256), 256, 0, stream>>>(Wq, Wqkvb, HID * HID / 4);
  k_f2b4<<<dim3((512 * HID / 4) / 256), 256, 0, stream>>>(Wk, Wqkvb + (size_t)2048 * HID, 512 * HID / 4);
  k_f2b4<<<dim3((512 * HID / 4) / 256), 256, 0, stream>>>(Wv, Wqkvb + (size_t)2560 * HID, 512 * HID / 4);
  k_f2b4<<<dim3((HID * HID / 4) / 256), 256, 0, stream>>>(Wo, Wob, HID * HID / 4);
  k_cs<<<dim3(S_LEN), dim3(64), 0, stream>>>(cs);
  k_gemm_bt<1><<<dim3(QKV_N / 128, MROWS / 128), 256, 0, stream>>>(xb, Wqkvb, qkv, MROWS, QKV_N, HID);
  k_rope<<<dim3(MROWS), 256, 0, stream>>>(qkv, cs, Qr, Kr, Vt);
  k_attn<<<dim3(16, BB * NHEADS), 256, 0, stream>>>(Qr, Kr, Vt, attn);
  k_gemm_bt<0><<<dim3(HID / 128, MROWS / 128), 256, 0, stream>>>(attn, Wob, out, MROWS, HID, HID);
}

// Round 3
// 277.792 us; speedup vs baseline: 1.4009x; 1.1839x over previous
//
#include <hip/hip_runtime.h>

typedef unsigned short u16;
typedef __bf16 bf16x8 __attribute__((ext_vector_type(8)));
typedef float f32x4 __attribute__((ext_vector_type(4)));

#define S_LEN  2048
#define NHEADS 16
#define NKVH   4
#define HDIM   128
#define BB     2
#define MROWS  4096   // B*S
#define QKV_N  3072   // NH*HD + 2*NKV*HD
#define HID    2048

__device__ __forceinline__ u16 f2b(float f) {
  union { float f; unsigned u; } x; x.f = f;
  unsigned r = x.u + 0x7fffu + ((x.u >> 16) & 1u);
  return (u16)(r >> 16);
}
__device__ __forceinline__ u16 f2b_fast(float f) {  // round-half-up, 2 ops
  union { float f; unsigned u; } x; x.f = f;
  return (u16)((x.u + 0x8000u) >> 16);
}
__device__ __forceinline__ float b2f(u16 v) {
  union { unsigned u; float f; } x; x.u = ((unsigned)v) << 16;
  return x.f;
}
__device__ __forceinline__ void gload_lds16(const u16* g, u16* l) {
  __builtin_amdgcn_global_load_lds((__attribute__((address_space(1))) void*)g,
                                   (__attribute__((address_space(3))) void*)l,
                                   16, 0, 0);
}

// fp32 -> bf16 conversion, 4 elements/thread
__global__ void k_f2b4(const float* __restrict__ in, u16* __restrict__ out, int n4) {
  int i = blockIdx.x * blockDim.x + threadIdx.x;
  if (i >= n4) return;
  float4 v = ((const float4*)in)[i];
  ushort4 o;
  o.x = f2b(v.x); o.y = f2b(v.y); o.z = f2b(v.z); o.w = f2b(v.w);
  ((ushort4*)out)[i] = o;
}

// RoPE cos/sin table
__global__ void k_cs(float* __restrict__ cs) {
  int s = blockIdx.x, j = threadIdx.x;  // 2048 x 64
  float inv = expf(-(float)j * 0.14391156831212787f);  // ln(10000)/64
  float ang = (float)s * inv;
  float c, sn;
  sincosf(ang, &sn, &c);
  cs[(s * 64 + j) * 2 + 0] = c;
  cs[(s * 64 + j) * 2 + 1] = sn;
}

// C[M][N] = A[M][K] * B[N][K]^T, bf16 in, bf16 or fp32 out. 128x128 tile, BK=32.
template <int OUT_BF16>
__global__ __launch_bounds__(256) void k_gemm_bt(
    const u16* __restrict__ A, const u16* __restrict__ Bm, void* __restrict__ Cv,
    int M, int N, int K)
{
  __shared__ u16 Al[128 * 32];
  __shared__ u16 Bl[128 * 32];
  const int tid = threadIdx.x;
  const int wave = tid >> 6, lane = tid & 63;
  const int l15 = lane & 15, l4 = lane >> 4;
  const int wr = wave >> 1, wc = wave & 1;
  const int row0 = blockIdx.y * 128, col0 = blockIdx.x * 128;

  f32x4 zero = {0.f, 0.f, 0.f, 0.f};
  f32x4 acc[4][4];
#pragma unroll
  for (int m = 0; m < 4; ++m)
#pragma unroll
    for (int n = 0; n < 4; ++n) acc[m][n] = zero;

  const int e0 = lane * 8;
  for (int kb = 0; kb < K; kb += 32) {
#pragma unroll
    for (int it = 0; it < 2; ++it) {
      const int chunk = it * 4 + wave;
      const int e = chunk * 512 + e0;
      const int r = e >> 5, c = e & 31;
      gload_lds16(A + (size_t)(row0 + r) * K + kb + c, Al + chunk * 512);
      gload_lds16(Bm + (size_t)(col0 + r) * K + kb + c, Bl + chunk * 512);
    }
    __syncthreads();
    bf16x8 af[4], bfv[4];
#pragma unroll
    for (int m = 0; m < 4; ++m)
      af[m] = *(const bf16x8*)(Al + (wr * 64 + m * 16 + l15) * 32 + l4 * 8);
#pragma unroll
    for (int n = 0; n < 4; ++n)
      bfv[n] = *(const bf16x8*)(Bl + (wc * 64 + n * 16 + l15) * 32 + l4 * 8);
#pragma unroll
    for (int m = 0; m < 4; ++m)
#pragma unroll
      for (int n = 0; n < 4; ++n)
        acc[m][n] = __builtin_amdgcn_mfma_f32_16x16x32_bf16(af[m], bfv[n], acc[m][n], 0, 0, 0);
    __syncthreads();
  }
#pragma unroll
  for (int m = 0; m < 4; ++m) {
    const int r = row0 + wr * 64 + m * 16 + l4 * 4;
#pragma unroll
    for (int n = 0; n < 4; ++n) {
      const int c = col0 + wc * 64 + n * 16 + l15;
#pragma unroll
      for (int j = 0; j < 4; ++j) {
        const float v = acc[m][n][j];
        if (OUT_BF16) ((u16*)Cv)[(size_t)(r + j) * N + c] = f2b(v);
        else          ((float*)Cv)[(size_t)(r + j) * N + c] = v;
      }
    }
  }
}

// RoPE + layout: qkv[row][3072] -> Qr[b][h][s][d], Kr[b][kvh][s][d], Vt[b][kvh][d][s]
__global__ __launch_bounds__(256) void k_rope(
    const u16* __restrict__ qkv, const float* __restrict__ cs,
    u16* __restrict__ Qr, u16* __restrict__ Kr, u16* __restrict__ Vt)
{
  const int row = blockIdx.x;
  const int b = row >> 11, s = row & 2047;
  const int t = threadIdx.x;
  const u16* src = qkv + (size_t)row * QKV_N;
#pragma unroll
  for (int p = t; p < 1024; p += 256) {
    const int h = p >> 6, j = p & 63;
    const float c = cs[(s * 64 + j) * 2], sn = cs[(s * 64 + j) * 2 + 1];
    const float x0 = b2f(src[h * 128 + j]);
    const float x1 = b2f(src[h * 128 + 64 + j]);
    const size_t base = ((size_t)(b * NHEADS + h) * S_LEN + s) * HDIM;
    Qr[base + j]      = f2b(x0 * c - x1 * sn);
    Qr[base + 64 + j] = f2b(x1 * c + x0 * sn);
  }
  {
    const int h = t >> 6, j = t & 63;
    const float c = cs[(s * 64 + j) * 2], sn = cs[(s * 64 + j) * 2 + 1];
    const float x0 = b2f(src[2048 + h * 128 + j]);
    const float x1 = b2f(src[2048 + h * 128 + 64 + j]);
    const size_t base = ((size_t)(b * NKVH + h) * S_LEN + s) * HDIM;
    Kr[base + j]      = f2b(x0 * c - x1 * sn);
    Kr[base + 64 + j] = f2b(x1 * c + x0 * sn);
  }
#pragma unroll
  for (int p = t; p < 512; p += 256) {
    const int h = p >> 7, d = p & 127;
    Vt[((size_t)(b * NKVH + h) * HDIM + d) * S_LEN + s] = src[2560 + p];
  }
}

// ---- flash attention v3: pipelined K-double/V-single LDS, paired q-tiles ----
__device__ __forceinline__ void attn_qtile(
    int qt, int lastPhase,
    const u16* __restrict__ Q, const u16* __restrict__ Kg, const u16* __restrict__ Vg,
    u16* __restrict__ Out, int bh,
    u16* Kl0, u16* Kl1, u16* Vlp, char* Pb,
    const int (&ko)[4], const int (&vo)[4],
    int wave, int lane, int& cur)
{
  const int l15 = lane & 15, l4 = lane >> 4;
  const int b = bh >> 4, h = bh & 15;
  const int qw0 = qt * 128 + wave * 32;
  const u16* Qg = Q + ((size_t)bh * S_LEN + qw0) * HDIM;

  bf16x8 qf[2][4];
#pragma unroll
  for (int m = 0; m < 2; ++m)
#pragma unroll
    for (int kc = 0; kc < 4; ++kc)
      qf[m][kc] = *(const bf16x8*)(Qg + (m * 16 + l15) * HDIM + kc * 32 + l4 * 8);

  f32x4 zero = {0.f, 0.f, 0.f, 0.f};
  f32x4 oacc[2][8];
#pragma unroll
  for (int m = 0; m < 2; ++m)
#pragma unroll
    for (int i = 0; i < 8; ++i) oacc[m][i] = zero;
  float m_r[2][4], l_p[2][4];
#pragma unroll
  for (int m = 0; m < 2; ++m)
#pragma unroll
    for (int j = 0; j < 4; ++j) { m_r[m][j] = -1e30f; l_p[m][j] = 0.f; }

  const float S2 = 0.08838834764831845f * 1.4426950408889634f;  // scale*log2e
  const int nt = 2 * (qt + 1);

  for (int t = 0; t < nt; ++t) {
    const int kt = t * 64;
    // issue V(t) stage (single buffer; consumed after mid-barrier)
#pragma unroll
    for (int it = 0; it < 4; ++it)
      gload_lds16(Vg + (size_t)vo[it] + kt, Vlp + (it * 4 + wave) * 512);
    // issue K(next) prefetch into the other K buffer
    const int hasNext = (t + 1 < nt) || (!lastPhase);
    const int ktn = (t + 1 < nt) ? kt + 64 : 0;  // phase A tail prefetches B's tile 0
    u16* Kn = cur ? Kl0 : Kl1;
    if (hasNext) {
#pragma unroll
      for (int it = 0; it < 4; ++it)
        gload_lds16(Kg + (size_t)ktn * HDIM + ko[it], Kn + (it * 4 + wave) * 512);
      asm volatile("s_waitcnt vmcnt(16)" ::: "memory");  // K(t) landed
    } else {
      asm volatile("s_waitcnt vmcnt(8)" ::: "memory");   // K(t) landed
    }
    __builtin_amdgcn_sched_barrier(0);
    __builtin_amdgcn_s_barrier();
    __builtin_amdgcn_sched_barrier(0);

    const char* Kb = (const char*)(cur ? Kl1 : Kl0);
    const int act = (kt <= qw0 + 31);
    float sv[2][4][4];
    if (act) {
      // ---- S = Q K^T ----
      f32x4 s[2][4];
#pragma unroll
      for (int m = 0; m < 2; ++m)
#pragma unroll
        for (int n = 0; n < 4; ++n) s[m][n] = zero;
#pragma unroll
      for (int n = 0; n < 4; ++n) {
        const int row = n * 16 + l15;
#pragma unroll
        for (int kc = 0; kc < 4; ++kc) {
          const int ab = (row * 256 + kc * 64 + l4 * 16) ^ ((row & 7) << 4);
          bf16x8 kf = *(const bf16x8*)(Kb + ab);
#pragma unroll
          for (int m = 0; m < 2; ++m)
            s[m][n] = __builtin_amdgcn_mfma_f32_16x16x32_bf16(qf[m][kc], kf, s[m][n], 0, 0, 0);
        }
      }
      // ---- scale (log2 domain) + causal mask + PER-LANE max ----
      const bool domask = (kt + 63 > qw0);
      float pm[2][4];
#pragma unroll
      for (int m = 0; m < 2; ++m)
#pragma unroll
        for (int j = 0; j < 4; ++j) {
          const int qg = qw0 + m * 16 + l4 * 4 + j;
#pragma unroll
          for (int n = 0; n < 4; ++n) {
            float x = s[m][n][j] * S2;
            if (domask && (kt + n * 16 + l15 > qg)) x = -1e30f;
            sv[m][n][j] = x;
          }
          pm[m][j] = fmaxf(fmaxf(sv[m][0][j], sv[m][1][j]),
                           fmaxf(sv[m][2][j], sv[m][3][j]));
        }
      // ---- defer-max: full reduce + rescale only when per-lane max grew past THR ----
      bool ok = true;
#pragma unroll
      for (int m = 0; m < 2; ++m)
#pragma unroll
        for (int j = 0; j < 4; ++j)
          ok = ok && (pm[m][j] <= m_r[m][j] + 11.5416f);  // 8 nats in log2 units
      if (!__all(ok)) {
#pragma unroll
        for (int off = 1; off < 16; off <<= 1)
#pragma unroll
          for (int m = 0; m < 2; ++m)
#pragma unroll
            for (int j = 0; j < 4; ++j)
              pm[m][j] = fmaxf(pm[m][j], __shfl_xor(pm[m][j], off, 64));
        float sc[2][4];
#pragma unroll
        for (int m = 0; m < 2; ++m)
#pragma unroll
          for (int j = 0; j < 4; ++j) {
            const float mn = fmaxf(m_r[m][j], pm[m][j]);
            sc[m][j] = exp2f(m_r[m][j] - mn);
            m_r[m][j] = mn;
            l_p[m][j] *= sc[m][j];
          }
#pragma unroll
        for (int m = 0; m < 2; ++m)
#pragma unroll
          for (int nd = 0; nd < 8; ++nd)
#pragma unroll
            for (int j = 0; j < 4; ++j) oacc[m][nd][j] *= sc[m][j];
      }
      // ---- P = exp2(sv - m), per-lane l accumulation, P -> LDS (swizzled) ----
#pragma unroll
      for (int m = 0; m < 2; ++m)
#pragma unroll
        for (int n = 0; n < 4; ++n)
#pragma unroll
          for (int j = 0; j < 4; ++j) {
            const float p = exp2f(sv[m][n][j] - m_r[m][j]);
            l_p[m][j] += p;
            const int prow = m * 16 + l4 * 4 + j;
            const int pb = (prow * 128 + (n * 16 + l15) * 2) ^ ((prow & 7) << 4);
            *(u16*)(Pb + pb) = f2b_fast(p);
          }
    }
    // ---- V(t) ready for everyone ----
    if (hasNext) asm volatile("s_waitcnt vmcnt(8)" ::: "memory");
    else         asm volatile("s_waitcnt vmcnt(0)" ::: "memory");
    __builtin_amdgcn_sched_barrier(0);
    __builtin_amdgcn_s_barrier();
    __builtin_amdgcn_sched_barrier(0);
    if (act) {
      // ---- O += P V ----
#pragma unroll
      for (int kc2 = 0; kc2 < 2; ++kc2) {
        bf16x8 pf[2];
#pragma unroll
        for (int m = 0; m < 2; ++m) {
          const int prow = m * 16 + l15;
          const int pb = (prow * 128 + kc2 * 64 + l4 * 16) ^ ((prow & 7) << 4);
          pf[m] = *(const bf16x8*)(Pb + pb);
        }
#pragma unroll
        for (int nd = 0; nd < 8; ++nd) {
          const int d = nd * 16 + l15;
          const int ab = (d * 128 + kc2 * 64 + l4 * 16) ^ ((d & 7) << 4);
          bf16x8 vf = *(const bf16x8*)((const char*)Vlp + ab);
#pragma unroll
          for (int m = 0; m < 2; ++m)
            oacc[m][nd] = __builtin_amdgcn_mfma_f32_16x16x32_bf16(pf[m], vf, oacc[m][nd], 0, 0, 0);
        }
      }
    }
    __builtin_amdgcn_sched_barrier(0);
    asm volatile("" ::: "memory");
    __builtin_amdgcn_s_barrier();   // all PV reads consumed; V/K buffers reusable
    __builtin_amdgcn_sched_barrier(0);
    cur ^= 1;
  }

  // ---- epilogue: reduce per-lane l, normalize, store ----
#pragma unroll
  for (int off = 1; off < 16; off <<= 1)
#pragma unroll
    for (int m = 0; m < 2; ++m)
#pragma unroll
      for (int j = 0; j < 4; ++j)
        l_p[m][j] += __shfl_xor(l_p[m][j], off, 64);
#pragma unroll
  for (int m = 0; m < 2; ++m) {
    float il[4];
#pragma unroll
    for (int j = 0; j < 4; ++j) il[j] = 1.f / l_p[m][j];
    const size_t obase = ((size_t)b * S_LEN + qw0 + m * 16 + l4 * 4) * HID + h * HDIM;
#pragma unroll
    for (int nd = 0; nd < 8; ++nd)
#pragma unroll
      for (int j = 0; j < 4; ++j)
        Out[obase + (size_t)j * HID + nd * 16 + l15] = f2b(oacc[m][nd][j] * il[j]);
  }
}

__global__ __launch_bounds__(256, 2) void k_attn(
    const u16* __restrict__ Q, const u16* __restrict__ Kr,
    const u16* __restrict__ Vt, u16* __restrict__ Out)
{
  __shared__ u16 Kl[2][64 * 128];   // 32 KB, double-buffered, XOR ^((kv&7)<<4)
  __shared__ u16 Vl[128 * 64];      // 16 KB, single buffer, XOR ^((d&7)<<4)
  __shared__ u16 Pl[4][32 * 64];    // 16 KB, per-wave P, XOR ^((q&7)<<4)
  const int tid = threadIdx.x;
  const int wave = tid >> 6, lane = tid & 63;
  const int bh = blockIdx.x;              // XCD = bh%8 -> 4 bh per XCD (KV L2-fit)
  const int pairi = blockIdx.y;           // q-tile pair (15-pairi, pairi): 34 tiles/block
  const int b = bh >> 4, h = bh & 15;
  const int kvh = h >> 2;

  const u16* Kg = Kr + (size_t)(b * NKVH + kvh) * S_LEN * HDIM;
  const u16* Vg = Vt + (size_t)(b * NKVH + kvh) * HDIM * S_LEN;

  // pre-swizzled source offsets (rule 21: linear LDS dest + inverse-swz source)
  int ko[4], vo[4];
#pragma unroll
  for (int it = 0; it < 4; ++it) {
    const int c = it * 4 + wave;
    const int L = c * 1024 + lane * 16;
    const int r = L >> 8;  const int w2 = (L & 255) ^ ((r & 7) << 4);
    ko[it] = r * HDIM + (w2 >> 1);
    const int d = L >> 7;  const int wv = (L & 127) ^ ((d & 7) << 4);
    vo[it] = d * S_LEN + (wv >> 1);
  }
  // prologue: stage K(0) of phase A
#pragma unroll
  for (int it = 0; it < 4; ++it)
    gload_lds16(Kg + ko[it], &Kl[0][(it * 4 + wave) * 512]);

  char* Pb = (char*)&Pl[wave][0];
  int cur = 0;
  attn_qtile(15 - pairi, 0, Q, Kg, Vg, Out, bh, &Kl[0][0], &Kl[1][0], Vl, Pb, ko, vo, wave, lane, cur);
  attn_qtile(pairi,      1, Q, Kg, Vg, Out, bh, &Kl[0][0], &Kl[1][0], Vl, Pb, ko, vo, wave, lane, cur);
}

extern "C" void kernel_launch(void* const* d_in, const int* in_sizes, int n_in,
                              void* d_out, int out_size, void* d_ws, size_t ws_size,
                              hipStream_t stream)
{
  const float* x  = (const float*)d_in[0];
  const float* Wq = (const float*)d_in[2];
  const float* Wk = (const float*)d_in[3];
  const float* Wv = (const float*)d_in[4];
  const float* Wo = (const float*)d_in[5];
  float* out = (float*)d_out;

  u16* xb    = (u16*)d_ws;
  u16* Wqkvb = xb    + (size_t)MROWS * HID;
  u16* Wob   = Wqkvb + (size_t)QKV_N * HID;
  u16* qkv   = Wob   + (size_t)HID * HID;
  u16* Qr    = qkv   + (size_t)MROWS * QKV_N;
  u16* Kr    = Qr    + (size_t)BB * NHEADS * S_LEN * HDIM;
  u16* Vt    = Kr    + (size_t)BB * NKVH * S_LEN * HDIM;
  u16* attn  = Vt    + (size_t)BB * NKVH * S_LEN * HDIM;
  float* cs  = (float*)(attn + (size_t)MROWS * HID);

  k_f2b4<<<dim3((MROWS * HID / 4) / 256), 256, 0, stream>>>(x, xb, MROWS * HID / 4);
  k_f2b4<<<dim3((HID * HID / 4) / 256), 256, 0, stream>>>(Wq, Wqkvb, HID * HID / 4);
  k_f2b4<<<dim3((512 * HID / 4) / 256), 256, 0, stream>>>(Wk, Wqkvb + (size_t)2048 * HID, 512 * HID / 4);
  k_f2b4<<<dim3((512 * HID / 4) / 256), 256, 0, stream>>>(Wv, Wqkvb + (size_t)2560 * HID, 512 * HID / 4);
  k_f2b4<<<dim3((HID * HID / 4) / 256), 256, 0, stream>>>(Wo, Wob, HID * HID / 4);
  k_cs<<<dim3(S_LEN), dim3(64), 0, stream>>>(cs);
  k_gemm_bt<1><<<dim3(QKV_N / 128, MROWS / 128), 256, 0, stream>>>(xb, Wqkvb, qkv, MROWS, QKV_N, HID);
  k_rope<<<dim3(MROWS), 256, 0, stream>>>(qkv, cs, Qr, Kr, Vt);
  k_attn<<<dim3(BB * NHEADS, 8), 256, 0, stream>>>(Qr, Kr, Vt, attn);
  k_gemm_bt<0><<<dim3(HID / 128, MROWS / 128), 256, 0, stream>>>(attn, Wob, out, MROWS, HID, HID);
}

// Round 4
// 237.280 us; speedup vs baseline: 1.6401x; 1.1707x over previous
//
#include <hip/hip_runtime.h>

typedef unsigned short u16;
typedef __bf16 bf16x8 __attribute__((ext_vector_type(8)));
typedef float f32x4 __attribute__((ext_vector_type(4)));

#define S_LEN  2048
#define NHEADS 16
#define NKVH   4
#define HDIM   128
#define BB     2
#define MROWS  4096   // B*S
#define QKV_N  3072   // NH*HD + 2*NKV*HD
#define HID    2048

__device__ __forceinline__ u16 f2b(float f) {
  union { float f; unsigned u; } x; x.f = f;
  unsigned r = x.u + 0x7fffu + ((x.u >> 16) & 1u);
  return (u16)(r >> 16);
}
__device__ __forceinline__ u16 f2b_fast(float f) {
  union { float f; unsigned u; } x; x.f = f;
  return (u16)((x.u + 0x8000u) >> 16);
}
__device__ __forceinline__ float b2f(u16 v) {
  union { unsigned u; float f; } x; x.u = ((unsigned)v) << 16;
  return x.f;
}
__device__ __forceinline__ void gload_lds16(const u16* g, u16* l) {
  __builtin_amdgcn_global_load_lds((__attribute__((address_space(1))) void*)g,
                                   (__attribute__((address_space(3))) void*)l,
                                   16, 0, 0);
}

// fp32 -> bf16 conversion, 4 elements/thread
__global__ void k_f2b4(const float* __restrict__ in, u16* __restrict__ out, int n4) {
  int i = blockIdx.x * blockDim.x + threadIdx.x;
  if (i >= n4) return;
  float4 v = ((const float4*)in)[i];
  ushort4 o;
  o.x = f2b(v.x); o.y = f2b(v.y); o.z = f2b(v.z); o.w = f2b(v.w);
  ((ushort4*)out)[i] = o;
}

// RoPE cos/sin table
__global__ void k_cs(float* __restrict__ cs) {
  int s = blockIdx.x, j = threadIdx.x;  // 2048 x 64
  float inv = expf(-(float)j * 0.14391156831212787f);  // ln(10000)/64
  float ang = (float)s * inv;
  float c, sn;
  sincosf(ang, &sn, &c);
  cs[(s * 64 + j) * 2 + 0] = c;
  cs[(s * 64 + j) * 2 + 1] = sn;
}

// C[M][N] = A[M][K] * B[N][K]^T, bf16 in, bf16 or fp32 out. 128x128 tile, BK=32.
template <int OUT_BF16>
__global__ __launch_bounds__(256) void k_gemm_bt(
    const u16* __restrict__ A, const u16* __restrict__ Bm, void* __restrict__ Cv,
    int M, int N, int K)
{
  __shared__ u16 Al[128 * 32];
  __shared__ u16 Bl[128 * 32];
  const int tid = threadIdx.x;
  const int wave = tid >> 6, lane = tid & 63;
  const int l15 = lane & 15, l4 = lane >> 4;
  const int wr = wave >> 1, wc = wave & 1;
  const int row0 = blockIdx.y * 128, col0 = blockIdx.x * 128;

  f32x4 zero = {0.f, 0.f, 0.f, 0.f};
  f32x4 acc[4][4];
#pragma unroll
  for (int m = 0; m < 4; ++m)
#pragma unroll
    for (int n = 0; n < 4; ++n) acc[m][n] = zero;

  const int e0 = lane * 8;
  for (int kb = 0; kb < K; kb += 32) {
#pragma unroll
    for (int it = 0; it < 2; ++it) {
      const int chunk = it * 4 + wave;
      const int e = chunk * 512 + e0;
      const int r = e >> 5, c = e & 31;
      gload_lds16(A + (size_t)(row0 + r) * K + kb + c, Al + chunk * 512);
      gload_lds16(Bm + (size_t)(col0 + r) * K + kb + c, Bl + chunk * 512);
    }
    __syncthreads();
    bf16x8 af[4], bfv[4];
#pragma unroll
    for (int m = 0; m < 4; ++m)
      af[m] = *(const bf16x8*)(Al + (wr * 64 + m * 16 + l15) * 32 + l4 * 8);
#pragma unroll
    for (int n = 0; n < 4; ++n)
      bfv[n] = *(const bf16x8*)(Bl + (wc * 64 + n * 16 + l15) * 32 + l4 * 8);
#pragma unroll
    for (int m = 0; m < 4; ++m)
#pragma unroll
      for (int n = 0; n < 4; ++n)
        acc[m][n] = __builtin_amdgcn_mfma_f32_16x16x32_bf16(af[m], bfv[n], acc[m][n], 0, 0, 0);
    __syncthreads();
  }
#pragma unroll
  for (int m = 0; m < 4; ++m) {
    const int r = row0 + wr * 64 + m * 16 + l4 * 4;
#pragma unroll
    for (int n = 0; n < 4; ++n) {
      const int c = col0 + wc * 64 + n * 16 + l15;
#pragma unroll
      for (int j = 0; j < 4; ++j) {
        const float v = acc[m][n][j];
        if (OUT_BF16) ((u16*)Cv)[(size_t)(r + j) * N + c] = f2b(v);
        else          ((float*)Cv)[(size_t)(r + j) * N + c] = v;
      }
    }
  }
}

// RoPE + layout for Q,K: qkv[row][3072] -> Qr[b][h][s][d], Kr[b][kvh][s][d]
__global__ __launch_bounds__(256) void k_rope(
    const u16* __restrict__ qkv, const float* __restrict__ cs,
    u16* __restrict__ Qr, u16* __restrict__ Kr)
{
  const int row = blockIdx.x;
  const int b = row >> 11, s = row & 2047;
  const int t = threadIdx.x;
  const u16* src = qkv + (size_t)row * QKV_N;
#pragma unroll
  for (int p = t; p < 1024; p += 256) {
    const int h = p >> 6, j = p & 63;
    const float c = cs[(s * 64 + j) * 2], sn = cs[(s * 64 + j) * 2 + 1];
    const float x0 = b2f(src[h * 128 + j]);
    const float x1 = b2f(src[h * 128 + 64 + j]);
    const size_t base = ((size_t)(b * NHEADS + h) * S_LEN + s) * HDIM;
    Qr[base + j]      = f2b(x0 * c - x1 * sn);
    Qr[base + 64 + j] = f2b(x1 * c + x0 * sn);
  }
  {
    const int h = t >> 6, j = t & 63;
    const float c = cs[(s * 64 + j) * 2], sn = cs[(s * 64 + j) * 2 + 1];
    const float x0 = b2f(src[2048 + h * 128 + j]);
    const float x1 = b2f(src[2048 + h * 128 + 64 + j]);
    const size_t base = ((size_t)(b * NKVH + h) * S_LEN + s) * HDIM;
    Kr[base + j]      = f2b(x0 * c - x1 * sn);
    Kr[base + 64 + j] = f2b(x1 * c + x0 * sn);
  }
}

// V transpose with 16-s blocking: full 32B stores (no partial-sector writes)
__global__ __launch_bounds__(256) void k_vtrans(
    const u16* __restrict__ qkv, u16* __restrict__ Vt)
{
  const int blk = blockIdx.x;              // b*128 + (s>>4)
  const int b = blk >> 7, s0 = (blk & 127) << 4;
  const int tid = threadIdx.x;
#pragma unroll
  for (int vi = 0; vi < 2; ++vi) {
    const int idx = vi * 256 + tid;        // 0..511  -> h=idx>>7, d=idx&127
    const int h = idx >> 7, d = idx & 127;
    union { u16 u[16]; uint4 v[2]; } bb;
#pragma unroll
    for (int s = 0; s < 16; ++s)
      bb.u[s] = qkv[(size_t)(b * S_LEN + s0 + s) * QKV_N + 2560 + idx];
    u16* dst = Vt + ((size_t)(b * NKVH + h) * HDIM + d) * S_LEN + s0;
    *(uint4*)(dst)     = bb.v[0];
    *(uint4*)(dst + 8) = bb.v[1];
  }
}

// ---- flash attention v4: 8 waves x 16 q-rows, K+V double-buffered LDS,
// ---- 2 barriers/tile, counted vmcnt, paired q-tiles, setprio on MFMA ----
__device__ __forceinline__ void attn_qtile(
    int qt, int lastPhase,
    const u16* __restrict__ Q, const u16* __restrict__ Kg, const u16* __restrict__ Vg,
    u16* __restrict__ Out, int bh,
    u16* Kl0, u16* Kl1, u16* Vl0, u16* Vl1, char* Pb,
    const int (&ko)[2], const int (&vo)[2],
    int wave, int lane, int& cur)
{
  const int l15 = lane & 15, l4 = lane >> 4;
  const int b = bh >> 4, h = bh & 15;
  const int qw0 = qt * 128 + wave * 16;
  const u16* Qg = Q + ((size_t)bh * S_LEN + qw0) * HDIM;

  bf16x8 qf[4];
#pragma unroll
  for (int kc = 0; kc < 4; ++kc)
    qf[kc] = *(const bf16x8*)(Qg + l15 * HDIM + kc * 32 + l4 * 8);

  f32x4 zero = {0.f, 0.f, 0.f, 0.f};
  f32x4 oacc[8];
#pragma unroll
  for (int i = 0; i < 8; ++i) oacc[i] = zero;
  float m_r[4], l_p[4];
#pragma unroll
  for (int j = 0; j < 4; ++j) { m_r[j] = -1e30f; l_p[j] = 0.f; }

  const float S2 = 0.08838834764831845f * 1.4426950408889634f;  // scale*log2e
  const int nt = 2 * (qt + 1);

  for (int t = 0; t < nt; ++t) {
    const int kt = t * 64;
    u16* Vb = cur ? Vl1 : Vl0;
    // issue V(t) into current V buffer (2 chunks/wave)
#pragma unroll
    for (int it = 0; it < 2; ++it)
      gload_lds16(Vg + (size_t)vo[it] + kt, Vb + (it * 8 + wave) * 512);
    // issue K(next) into the other K buffer
    const int hasNext = (t + 1 < nt) || (!lastPhase);
    const int ktn = (t + 1 < nt) ? kt + 64 : 0;  // phase A tail prefetches B tile 0
    u16* Kn = cur ? Kl0 : Kl1;
    if (hasNext) {
#pragma unroll
      for (int it = 0; it < 2; ++it)
        gload_lds16(Kg + (size_t)ktn * HDIM + ko[it], Kn + (it * 8 + wave) * 512);
      asm volatile("s_waitcnt vmcnt(4)" ::: "memory");  // K(t) landed
    } else {
      asm volatile("s_waitcnt vmcnt(2)" ::: "memory");
    }
    __builtin_amdgcn_sched_barrier(0);
    __builtin_amdgcn_s_barrier();
    __builtin_amdgcn_sched_barrier(0);

    const char* Kb = (const char*)(cur ? Kl1 : Kl0);
    const int act = (kt <= qw0 + 15);
    if (act) {
      // ---- S = Q K^T : [16 q][64 k] ----
      f32x4 s[4];
#pragma unroll
      for (int n = 0; n < 4; ++n) s[n] = zero;
      __builtin_amdgcn_s_setprio(1);
#pragma unroll
      for (int n = 0; n < 4; ++n) {
        const int row = n * 16 + l15;
#pragma unroll
        for (int kc = 0; kc < 4; ++kc) {
          const int ab = (row * 256 + kc * 64 + l4 * 16) ^ ((row & 7) << 4);
          bf16x8 kf = *(const bf16x8*)(Kb + ab);
          s[n] = __builtin_amdgcn_mfma_f32_16x16x32_bf16(qf[kc], kf, s[n], 0, 0, 0);
        }
      }
      __builtin_amdgcn_s_setprio(0);
      // ---- scale (log2 domain) + (rare) causal mask + per-lane max ----
      float sv[4][4], pm[4];
      if (kt + 63 > qw0) {        // masked tile: ~1 of 17 per wave
#pragma unroll
        for (int j = 0; j < 4; ++j) {
          const int qg = qw0 + l4 * 4 + j;
#pragma unroll
          for (int n = 0; n < 4; ++n) {
            float x = s[n][j] * S2;
            if (kt + n * 16 + l15 > qg) x = -1e30f;
            sv[n][j] = x;
          }
        }
      } else {
#pragma unroll
        for (int j = 0; j < 4; ++j)
#pragma unroll
          for (int n = 0; n < 4; ++n) sv[n][j] = s[n][j] * S2;
      }
#pragma unroll
      for (int j = 0; j < 4; ++j)
        pm[j] = fmaxf(fmaxf(sv[0][j], sv[1][j]), fmaxf(sv[2][j], sv[3][j]));
      // ---- defer-max ----
      bool ok = true;
#pragma unroll
      for (int j = 0; j < 4; ++j) ok = ok && (pm[j] <= m_r[j] + 11.5416f);
      if (!__all(ok)) {
#pragma unroll
        for (int off = 1; off < 16; off <<= 1)
#pragma unroll
          for (int j = 0; j < 4; ++j)
            pm[j] = fmaxf(pm[j], __shfl_xor(pm[j], off, 64));
        float sc[4];
#pragma unroll
        for (int j = 0; j < 4; ++j) {
          const float mn = fmaxf(m_r[j], pm[j]);
          sc[j] = exp2f(m_r[j] - mn);
          m_r[j] = mn;
          l_p[j] *= sc[j];
        }
#pragma unroll
        for (int nd = 0; nd < 8; ++nd)
#pragma unroll
          for (int j = 0; j < 4; ++j) oacc[nd][j] *= sc[j];
      }
      // ---- P = exp2(sv - m), per-lane l, P -> LDS (swizzled) ----
#pragma unroll
      for (int n = 0; n < 4; ++n)
#pragma unroll
        for (int j = 0; j < 4; ++j) {
          const float p = exp2f(sv[n][j] - m_r[j]);
          l_p[j] += p;
          const int prow = l4 * 4 + j;
          const int pb = (prow * 128 + (n * 16 + l15) * 2) ^ ((prow & 7) << 4);
          *(u16*)(Pb + pb) = f2b_fast(p);
        }
    }
    // ---- V(t) ready ----
    if (hasNext) asm volatile("s_waitcnt vmcnt(2)" ::: "memory");
    else         asm volatile("s_waitcnt vmcnt(0)" ::: "memory");
    __builtin_amdgcn_sched_barrier(0);
    __builtin_amdgcn_s_barrier();
    __builtin_amdgcn_sched_barrier(0);
    if (act) {
      // ---- O += P V ----
      __builtin_amdgcn_s_setprio(1);
#pragma unroll
      for (int kc2 = 0; kc2 < 2; ++kc2) {
        const int prow = l15;
        const int pbo = (prow * 128 + kc2 * 64 + l4 * 16) ^ ((prow & 7) << 4);
        bf16x8 pf = *(const bf16x8*)(Pb + pbo);
#pragma unroll
        for (int nd = 0; nd < 8; ++nd) {
          const int d = nd * 16 + l15;
          const int ab = (d * 128 + kc2 * 64 + l4 * 16) ^ ((d & 7) << 4);
          bf16x8 vf = *(const bf16x8*)((const char*)Vb + ab);
          oacc[nd] = __builtin_amdgcn_mfma_f32_16x16x32_bf16(pf, vf, oacc[nd], 0, 0, 0);
        }
      }
      __builtin_amdgcn_s_setprio(0);
    }
    cur ^= 1;
  }

  // ---- epilogue ----
#pragma unroll
  for (int off = 1; off < 16; off <<= 1)
#pragma unroll
    for (int j = 0; j < 4; ++j)
      l_p[j] += __shfl_xor(l_p[j], off, 64);
  float il[4];
#pragma unroll
  for (int j = 0; j < 4; ++j) il[j] = 1.f / l_p[j];
  const size_t obase = ((size_t)b * S_LEN + qw0 + l4 * 4) * HID + h * HDIM;
#pragma unroll
  for (int nd = 0; nd < 8; ++nd)
#pragma unroll
    for (int j = 0; j < 4; ++j)
      Out[obase + (size_t)j * HID + nd * 16 + l15] = f2b(oacc[nd][j] * il[j]);
}

__global__ __launch_bounds__(512) void k_attn(
    const u16* __restrict__ Q, const u16* __restrict__ Kr,
    const u16* __restrict__ Vt, u16* __restrict__ Out)
{
  __shared__ u16 Kl[2][64 * 128];   // 32 KB dbuf, XOR ^((kv&7)<<4)
  __shared__ u16 Vl[2][128 * 64];   // 32 KB dbuf, XOR ^((d&7)<<4)
  __shared__ u16 Pl[8][16 * 64];    // 16 KB per-wave P, XOR ^((q&7)<<4)
  const int tid = threadIdx.x;
  const int wave = tid >> 6, lane = tid & 63;
  const int bh = blockIdx.x;              // XCD = bh%8: KV L2 locality
  const int pairi = blockIdx.y;           // q-tile pair (15-pairi, pairi): 34 tiles
  const int b = bh >> 4, h = bh & 15;
  const int kvh = h >> 2;

  const u16* Kg = Kr + (size_t)(b * NKVH + kvh) * S_LEN * HDIM;
  const u16* Vg = Vt + (size_t)(b * NKVH + kvh) * HDIM * S_LEN;

  // pre-swizzled source offsets (rule 21)
  int ko[2], vo[2];
#pragma unroll
  for (int it = 0; it < 2; ++it) {
    const int c = it * 8 + wave;
    const int L = c * 1024 + lane * 16;
    const int r = L >> 8;  const int w2 = (L & 255) ^ ((r & 7) << 4);
    ko[it] = r * HDIM + (w2 >> 1);
    const int d = L >> 7;  const int wv = (L & 127) ^ ((d & 7) << 4);
    vo[it] = d * S_LEN + (wv >> 1);
  }
  // prologue: stage K(0) of phase A
#pragma unroll
  for (int it = 0; it < 2; ++it)
    gload_lds16(Kg + ko[it], &Kl[0][(it * 8 + wave) * 512]);

  char* Pb = (char*)&Pl[wave][0];
  int cur = 0;
  attn_qtile(15 - pairi, 0, Q, Kg, Vg, Out, bh, &Kl[0][0], &Kl[1][0],
             &Vl[0][0], &Vl[1][0], Pb, ko, vo, wave, lane, cur);
  attn_qtile(pairi,      1, Q, Kg, Vg, Out, bh, &Kl[0][0], &Kl[1][0],
             &Vl[0][0], &Vl[1][0], Pb, ko, vo, wave, lane, cur);
}

extern "C" void kernel_launch(void* const* d_in, const int* in_sizes, int n_in,
                              void* d_out, int out_size, void* d_ws, size_t ws_size,
                              hipStream_t stream)
{
  const float* x  = (const float*)d_in[0];
  const float* Wq = (const float*)d_in[2];
  const float* Wk = (const float*)d_in[3];
  const float* Wv = (const float*)d_in[4];
  const float* Wo = (const float*)d_in[5];
  float* out = (float*)d_out;

  u16* xb    = (u16*)d_ws;
  u16* Wqkvb = xb    + (size_t)MROWS * HID;
  u16* Wob   = Wqkvb + (size_t)QKV_N * HID;
  u16* qkv   = Wob   + (size_t)HID * HID;
  u16* Qr    = qkv   + (size_t)MROWS * QKV_N;
  u16* Kr    = Qr    + (size_t)BB * NHEADS * S_LEN * HDIM;
  u16* Vt    = Kr    + (size_t)BB * NKVH * S_LEN * HDIM;
  u16* attn  = Vt    + (size_t)BB * NKVH * S_LEN * HDIM;
  float* cs  = (float*)(attn + (size_t)MROWS * HID);

  k_f2b4<<<dim3((MROWS * HID / 4) / 256), 256, 0, stream>>>(x, xb, MROWS * HID / 4);
  k_f2b4<<<dim3((HID * HID / 4) / 256), 256, 0, stream>>>(Wq, Wqkvb, HID * HID / 4);
  k_f2b4<<<dim3((512 * HID / 4) / 256), 256, 0, stream>>>(Wk, Wqkvb + (size_t)2048 * HID, 512 * HID / 4);
  k_f2b4<<<dim3((512 * HID / 4) / 256), 256, 0, stream>>>(Wv, Wqkvb + (size_t)2560 * HID, 512 * HID / 4);
  k_f2b4<<<dim3((HID * HID / 4) / 256), 256, 0, stream>>>(Wo, Wob, HID * HID / 4);
  k_cs<<<dim3(S_LEN), dim3(64), 0, stream>>>(cs);
  k_gemm_bt<1><<<dim3(QKV_N / 128, MROWS / 128), 256, 0, stream>>>(xb, Wqkvb, qkv, MROWS, QKV_N, HID);
  k_rope<<<dim3(MROWS), 256, 0, stream>>>(qkv, cs, Qr, Kr);
  k_vtrans<<<dim3(BB * 128), 256, 0, stream>>>(qkv, Vt);
  k_attn<<<dim3(BB * NHEADS, 8), 512, 0, stream>>>(Qr, Kr, Vt, attn);
  k_gemm_bt<0><<<dim3(HID / 128, MROWS / 128), 256, 0, stream>>>(attn, Wob, out, MROWS, HID, HID);
}

// Round 5
// 235.364 us; speedup vs baseline: 1.6535x; 1.0081x over previous
//
#include <hip/hip_runtime.h>

typedef unsigned short u16;
typedef __bf16 bf16x8 __attribute__((ext_vector_type(8)));
typedef float f32x4 __attribute__((ext_vector_type(4)));

#define S_LEN  2048
#define NHEADS 16
#define NKVH   4
#define HDIM   128
#define BB     2
#define MROWS  4096   // B*S
#define QKV_N  3072   // NH*HD + 2*NKV*HD
#define HID    2048

__device__ __forceinline__ u16 f2b(float f) {
  union { float f; unsigned u; } x; x.f = f;
  unsigned r = x.u + 0x7fffu + ((x.u >> 16) & 1u);
  return (u16)(r >> 16);
}
__device__ __forceinline__ u16 f2b_fast(float f) {
  union { float f; unsigned u; } x; x.f = f;
  return (u16)((x.u + 0x8000u) >> 16);
}
__device__ __forceinline__ float b2f(u16 v) {
  union { unsigned u; float f; } x; x.u = ((unsigned)v) << 16;
  return x.f;
}
__device__ __forceinline__ void gload_lds16(const u16* g, u16* l) {
  __builtin_amdgcn_global_load_lds((__attribute__((address_space(1))) void*)g,
                                   (__attribute__((address_space(3))) void*)l,
                                   16, 0, 0);
}

// ---- one-launch prep: all fp32->bf16 converts + RoPE cos/sin table ----
#define PB_X   8192                // x: 4096*2048/4/256
#define PB_WQ  (PB_X + 4096)       // Wq: 2048*2048/4/256
#define PB_WK  (PB_WQ + 1024)      // Wk: 512*2048/4/256
#define PB_WV  (PB_WK + 1024)
#define PB_WO  (PB_WV + 4096)
#define PB_CS  (PB_WO + 512)       // cs: 2048*64/256
__global__ void k_prep(const float* __restrict__ x,
                       const float* __restrict__ Wq, const float* __restrict__ Wk,
                       const float* __restrict__ Wv, const float* __restrict__ Wo,
                       u16* __restrict__ xb, u16* __restrict__ Wqkvb,
                       u16* __restrict__ Wob, float* __restrict__ cs)
{
  const int bid = blockIdx.x, tid = threadIdx.x;
  const float* src; u16* dst; int i;
  if (bid < PB_X)       { i = bid * 256 + tid;            src = x;  dst = xb; }
  else if (bid < PB_WQ) { i = (bid - PB_X) * 256 + tid;   src = Wq; dst = Wqkvb; }
  else if (bid < PB_WK) { i = (bid - PB_WQ) * 256 + tid;  src = Wk; dst = Wqkvb + (size_t)2048 * HID; }
  else if (bid < PB_WV) { i = (bid - PB_WK) * 256 + tid;  src = Wv; dst = Wqkvb + (size_t)2560 * HID; }
  else if (bid < PB_WO) { i = (bid - PB_WV) * 256 + tid;  src = Wo; dst = Wob; }
  else {
    const int p = (bid - PB_WO) * 256 + tid;   // s*64 + j
    const int s = p >> 6, j = p & 63;
    float inv = expf(-(float)j * 0.14391156831212787f);  // ln(10000)/64
    float ang = (float)s * inv;
    float c, sn; sincosf(ang, &sn, &c);
    cs[p * 2 + 0] = c; cs[p * 2 + 1] = sn;
    return;
  }
  float4 v = ((const float4*)src)[i];
  ushort4 o;
  o.x = f2b(v.x); o.y = f2b(v.y); o.z = f2b(v.z); o.w = f2b(v.w);
  ((ushort4*)dst)[i] = o;
}

// C[M][N] = A[M][K] * B[N][K]^T, bf16 in, bf16 or fp32 out. 128x128 tile, BK=32.
template <int OUT_BF16>
__global__ __launch_bounds__(256) void k_gemm_bt(
    const u16* __restrict__ A, const u16* __restrict__ Bm, void* __restrict__ Cv,
    int M, int N, int K)
{
  __shared__ u16 Al[128 * 32];
  __shared__ u16 Bl[128 * 32];
  const int tid = threadIdx.x;
  const int wave = tid >> 6, lane = tid & 63;
  const int l15 = lane & 15, l4 = lane >> 4;
  const int wr = wave >> 1, wc = wave & 1;
  const int row0 = blockIdx.y * 128, col0 = blockIdx.x * 128;

  f32x4 zero = {0.f, 0.f, 0.f, 0.f};
  f32x4 acc[4][4];
#pragma unroll
  for (int m = 0; m < 4; ++m)
#pragma unroll
    for (int n = 0; n < 4; ++n) acc[m][n] = zero;

  const int e0 = lane * 8;
  for (int kb = 0; kb < K; kb += 32) {
#pragma unroll
    for (int it = 0; it < 2; ++it) {
      const int chunk = it * 4 + wave;
      const int e = chunk * 512 + e0;
      const int r = e >> 5, c = e & 31;
      gload_lds16(A + (size_t)(row0 + r) * K + kb + c, Al + chunk * 512);
      gload_lds16(Bm + (size_t)(col0 + r) * K + kb + c, Bl + chunk * 512);
    }
    __syncthreads();
    bf16x8 af[4], bfv[4];
#pragma unroll
    for (int m = 0; m < 4; ++m)
      af[m] = *(const bf16x8*)(Al + (wr * 64 + m * 16 + l15) * 32 + l4 * 8);
#pragma unroll
    for (int n = 0; n < 4; ++n)
      bfv[n] = *(const bf16x8*)(Bl + (wc * 64 + n * 16 + l15) * 32 + l4 * 8);
#pragma unroll
    for (int m = 0; m < 4; ++m)
#pragma unroll
      for (int n = 0; n < 4; ++n)
        acc[m][n] = __builtin_amdgcn_mfma_f32_16x16x32_bf16(af[m], bfv[n], acc[m][n], 0, 0, 0);
    __syncthreads();
  }
#pragma unroll
  for (int m = 0; m < 4; ++m) {
    const int r = row0 + wr * 64 + m * 16 + l4 * 4;
#pragma unroll
    for (int n = 0; n < 4; ++n) {
      const int c = col0 + wc * 64 + n * 16 + l15;
#pragma unroll
      for (int j = 0; j < 4; ++j) {
        const float v = acc[m][n][j];
        if (OUT_BF16) ((u16*)Cv)[(size_t)(r + j) * N + c] = f2b(v);
        else          ((float*)Cv)[(size_t)(r + j) * N + c] = v;
      }
    }
  }
}

// ---- fused RoPE (Q pre-scaled by softmax scale) + K RoPE + V transpose ----
// block = (b, 8-s slab); Qr[b][h][s][d], Kr[b][kvh][s][d], Vt[b][kvh][d][s]
__global__ __launch_bounds__(256) void k_ropev(
    const u16* __restrict__ qkv, const float* __restrict__ cs,
    u16* __restrict__ Qr, u16* __restrict__ Kr, u16* __restrict__ Vt)
{
  const int blk = blockIdx.x;            // b*256 + (s>>3)
  const int b = blk >> 8, s0 = (blk & 255) << 3;
  const int tid = threadIdx.x;
  const float S2 = 0.08838834764831845f * 1.4426950408889634f;  // scale*log2e
  // Q: 8 s x 16 h x 64 j
#pragma unroll
  for (int p = tid; p < 8192; p += 256) {
    const int s = p >> 10, rem = p & 1023, h = rem >> 6, j = rem & 63;
    const int sg = s0 + s;
    const float c = cs[(sg * 64 + j) * 2], sn = cs[(sg * 64 + j) * 2 + 1];
    const u16* src = qkv + (size_t)(b * S_LEN + sg) * QKV_N + h * 128;
    const float x0 = b2f(src[j]), x1 = b2f(src[64 + j]);
    const size_t base = ((size_t)(b * NHEADS + h) * S_LEN + sg) * HDIM;
    Qr[base + j]      = f2b((x0 * c - x1 * sn) * S2);
    Qr[base + 64 + j] = f2b((x1 * c + x0 * sn) * S2);
  }
  // K: 8 s x 4 h x 64 j
#pragma unroll
  for (int p = tid; p < 2048; p += 256) {
    const int s = p >> 8, rem = p & 255, h = rem >> 6, j = rem & 63;
    const int sg = s0 + s;
    const float c = cs[(sg * 64 + j) * 2], sn = cs[(sg * 64 + j) * 2 + 1];
    const u16* src = qkv + (size_t)(b * S_LEN + sg) * QKV_N + 2048 + h * 128;
    const float x0 = b2f(src[j]), x1 = b2f(src[64 + j]);
    const size_t base = ((size_t)(b * NKVH + h) * S_LEN + sg) * HDIM;
    Kr[base + j]      = f2b(x0 * c - x1 * sn);
    Kr[base + 64 + j] = f2b(x1 * c + x0 * sn);
  }
  // V transpose: 512 (h,d) cols x 8 s -> one 16B store each
#pragma unroll
  for (int vi = 0; vi < 2; ++vi) {
    const int idx = vi * 256 + tid, h = idx >> 7, d = idx & 127;
    union { u16 u[8]; uint4 v; } bb;
#pragma unroll
    for (int s = 0; s < 8; ++s)
      bb.u[s] = qkv[(size_t)(b * S_LEN + s0 + s) * QKV_N + 2560 + idx];
    *(uint4*)(Vt + ((size_t)(b * NKVH + h) * HDIM + d) * S_LEN + s0) = bb.v;
  }
}

// ---- flash attention v5: 4 waves x 16 q-rows (QBLK=64), 512 blocks = 2/CU,
// ---- K+V dbuf LDS, 2 barriers/tile, counted vmcnt, paired q-tiles ----
__device__ __forceinline__ void attn_qtile(
    int qt, int lastPhase,
    const u16* __restrict__ Q, const u16* __restrict__ Kg, const u16* __restrict__ Vg,
    u16* __restrict__ Out, int bh,
    u16* Kl0, u16* Kl1, u16* Vl0, u16* Vl1, char* Pb,
    const int (&ko)[4], const int (&vo)[4],
    int wave, int lane, int& cur)
{
  const int l15 = lane & 15, l4 = lane >> 4;
  const int b = bh >> 4, h = bh & 15;
  const int qw0 = qt * 64 + wave * 16;
  const u16* Qg = Q + ((size_t)bh * S_LEN + qw0) * HDIM;

  bf16x8 qf[4];
#pragma unroll
  for (int kc = 0; kc < 4; ++kc)
    qf[kc] = *(const bf16x8*)(Qg + l15 * HDIM + kc * 32 + l4 * 8);

  f32x4 zero = {0.f, 0.f, 0.f, 0.f};
  f32x4 oacc[8];
#pragma unroll
  for (int i = 0; i < 8; ++i) oacc[i] = zero;
  float m_r[4], l_p[4];
#pragma unroll
  for (int j = 0; j < 4; ++j) { m_r[j] = -1e30f; l_p[j] = 0.f; }

  const int nt = qt + 1;

  for (int t = 0; t < nt; ++t) {
    const int kt = t * 64;
    u16* Vb = cur ? Vl1 : Vl0;
    // issue V(t) into current V buffer (4 chunks/wave)
#pragma unroll
    for (int it = 0; it < 4; ++it)
      gload_lds16(Vg + (size_t)vo[it] + kt, Vb + (it * 4 + wave) * 512);
    // issue K(next) into the other K buffer
    const int hasNext = (t + 1 < nt) || (!lastPhase);
    const int ktn = (t + 1 < nt) ? kt + 64 : 0;  // phase A tail prefetches B tile 0
    u16* Kn = cur ? Kl0 : Kl1;
    if (hasNext) {
#pragma unroll
      for (int it = 0; it < 4; ++it)
        gload_lds16(Kg + (size_t)ktn * HDIM + ko[it], Kn + (it * 4 + wave) * 512);
      asm volatile("s_waitcnt vmcnt(8)" ::: "memory");  // K(t) landed
    } else {
      asm volatile("s_waitcnt vmcnt(4)" ::: "memory");
    }
    __builtin_amdgcn_sched_barrier(0);
    __builtin_amdgcn_s_barrier();
    __builtin_amdgcn_sched_barrier(0);

    const char* Kb = (const char*)(cur ? Kl1 : Kl0);
    {
      // ---- S = Q K^T : [16 q][64 k] (Q pre-scaled) ----
      f32x4 s[4];
#pragma unroll
      for (int n = 0; n < 4; ++n) s[n] = zero;
      __builtin_amdgcn_s_setprio(1);
#pragma unroll
      for (int n = 0; n < 4; ++n) {
        const int row = n * 16 + l15;
#pragma unroll
        for (int kc = 0; kc < 4; ++kc) {
          const int ab = (row * 256 + kc * 64 + l4 * 16) ^ ((row & 7) << 4);
          bf16x8 kf = *(const bf16x8*)(Kb + ab);
          s[n] = __builtin_amdgcn_mfma_f32_16x16x32_bf16(qf[kc], kf, s[n], 0, 0, 0);
        }
      }
      __builtin_amdgcn_s_setprio(0);
      // ---- (rare) causal mask + per-lane max ----
      float sv[4][4], pm[4];
      if (kt + 63 > qw0) {   // only the last tile per wave
#pragma unroll
        for (int j = 0; j < 4; ++j) {
          const int qg = qw0 + l4 * 4 + j;
#pragma unroll
          for (int n = 0; n < 4; ++n) {
            float x = s[n][j];
            if (kt + n * 16 + l15 > qg) x = -1e30f;
            sv[n][j] = x;
          }
        }
      } else {
#pragma unroll
        for (int j = 0; j < 4; ++j)
#pragma unroll
          for (int n = 0; n < 4; ++n) sv[n][j] = s[n][j];
      }
#pragma unroll
      for (int j = 0; j < 4; ++j)
        pm[j] = fmaxf(fmaxf(sv[0][j], sv[1][j]), fmaxf(sv[2][j], sv[3][j]));
      // ---- defer-max ----
      bool ok = true;
#pragma unroll
      for (int j = 0; j < 4; ++j) ok = ok && (pm[j] <= m_r[j] + 11.5416f);
      if (!__all(ok)) {
#pragma unroll
        for (int off = 1; off < 16; off <<= 1)
#pragma unroll
          for (int j = 0; j < 4; ++j)
            pm[j] = fmaxf(pm[j], __shfl_xor(pm[j], off, 64));
        float sc[4];
#pragma unroll
        for (int j = 0; j < 4; ++j) {
          const float mn = fmaxf(m_r[j], pm[j]);
          sc[j] = exp2f(m_r[j] - mn);
          m_r[j] = mn;
          l_p[j] *= sc[j];
        }
#pragma unroll
        for (int nd = 0; nd < 8; ++nd)
#pragma unroll
          for (int j = 0; j < 4; ++j) oacc[nd][j] *= sc[j];
      }
      // ---- P = exp2(sv - m), per-lane l, P -> LDS (swizzled) ----
#pragma unroll
      for (int n = 0; n < 4; ++n)
#pragma unroll
        for (int j = 0; j < 4; ++j) {
          const float p = exp2f(sv[n][j] - m_r[j]);
          l_p[j] += p;
          const int prow = l4 * 4 + j;
          const int pb = (prow * 128 + (n * 16 + l15) * 2) ^ ((prow & 7) << 4);
          *(u16*)(Pb + pb) = f2b_fast(p);
        }
    }
    // ---- V(t) ready ----
    if (hasNext) asm volatile("s_waitcnt vmcnt(4)" ::: "memory");
    else         asm volatile("s_waitcnt vmcnt(0)" ::: "memory");
    __builtin_amdgcn_sched_barrier(0);
    __builtin_amdgcn_s_barrier();
    __builtin_amdgcn_sched_barrier(0);
    {
      // ---- O += P V ----
      __builtin_amdgcn_s_setprio(1);
#pragma unroll
      for (int kc2 = 0; kc2 < 2; ++kc2) {
        const int prow = l15;
        const int pbo = (prow * 128 + kc2 * 64 + l4 * 16) ^ ((prow & 7) << 4);
        bf16x8 pf = *(const bf16x8*)(Pb + pbo);
#pragma unroll
        for (int nd = 0; nd < 8; ++nd) {
          const int d = nd * 16 + l15;
          const int ab = (d * 128 + kc2 * 64 + l4 * 16) ^ ((d & 7) << 4);
          bf16x8 vf = *(const bf16x8*)((const char*)Vb + ab);
          oacc[nd] = __builtin_amdgcn_mfma_f32_16x16x32_bf16(pf, vf, oacc[nd], 0, 0, 0);
        }
      }
      __builtin_amdgcn_s_setprio(0);
    }
    cur ^= 1;
  }

  // ---- epilogue ----
#pragma unroll
  for (int off = 1; off < 16; off <<= 1)
#pragma unroll
    for (int j = 0; j < 4; ++j)
      l_p[j] += __shfl_xor(l_p[j], off, 64);
  float il[4];
#pragma unroll
  for (int j = 0; j < 4; ++j) il[j] = 1.f / l_p[j];
  const size_t obase = ((size_t)b * S_LEN + qw0 + l4 * 4) * HID + h * HDIM;
#pragma unroll
  for (int nd = 0; nd < 8; ++nd)
#pragma unroll
    for (int j = 0; j < 4; ++j)
      Out[obase + (size_t)j * HID + nd * 16 + l15] = f2b(oacc[nd][j] * il[j]);
}

__global__ __launch_bounds__(256) void k_attn(
    const u16* __restrict__ Q, const u16* __restrict__ Kr,
    const u16* __restrict__ Vt, u16* __restrict__ Out)
{
  __shared__ u16 Kl[2][64 * 128];   // 32 KB dbuf, XOR ^((kv&7)<<4)
  __shared__ u16 Vl[2][128 * 64];   // 32 KB dbuf, XOR ^((d&7)<<4)
  __shared__ u16 Pl[4][16 * 64];    // 8 KB per-wave P, XOR ^((q&7)<<4)
  const int tid = threadIdx.x;
  const int wave = tid >> 6, lane = tid & 63;
  const int bh = blockIdx.x;              // XCD = bh%8: KV L2 locality
  const int pairi = blockIdx.y;           // pair (31-pairi, pairi): 33 tiles/block
  const int b = bh >> 4, h = bh & 15;
  const int kvh = h >> 2;

  const u16* Kg = Kr + (size_t)(b * NKVH + kvh) * S_LEN * HDIM;
  const u16* Vg = Vt + (size_t)(b * NKVH + kvh) * HDIM * S_LEN;

  // pre-swizzled source offsets (rule 21)
  int ko[4], vo[4];
#pragma unroll
  for (int it = 0; it < 4; ++it) {
    const int c = it * 4 + wave;
    const int L = c * 1024 + lane * 16;
    const int r = L >> 8;  const int w2 = (L & 255) ^ ((r & 7) << 4);
    ko[it] = r * HDIM + (w2 >> 1);
    const int d = L >> 7;  const int wv = (L & 127) ^ ((d & 7) << 4);
    vo[it] = d * S_LEN + (wv >> 1);
  }
  // prologue: stage K(0) of phase A
#pragma unroll
  for (int it = 0; it < 4; ++it)
    gload_lds16(Kg + ko[it], &Kl[0][(it * 4 + wave) * 512]);

  char* Pb = (char*)&Pl[wave][0];
  int cur = 0;
  attn_qtile(31 - pairi, 0, Q, Kg, Vg, Out, bh, &Kl[0][0], &Kl[1][0],
             &Vl[0][0], &Vl[1][0], Pb, ko, vo, wave, lane, cur);
  attn_qtile(pairi,      1, Q, Kg, Vg, Out, bh, &Kl[0][0], &Kl[1][0],
             &Vl[0][0], &Vl[1][0], Pb, ko, vo, wave, lane, cur);
}

extern "C" void kernel_launch(void* const* d_in, const int* in_sizes, int n_in,
                              void* d_out, int out_size, void* d_ws, size_t ws_size,
                              hipStream_t stream)
{
  const float* x  = (const float*)d_in[0];
  const float* Wq = (const float*)d_in[2];
  const float* Wk = (const float*)d_in[3];
  const float* Wv = (const float*)d_in[4];
  const float* Wo = (const float*)d_in[5];
  float* out = (float*)d_out;

  u16* xb    = (u16*)d_ws;
  u16* Wqkvb = xb    + (size_t)MROWS * HID;
  u16* Wob   = Wqkvb + (size_t)QKV_N * HID;
  u16* qkv   = Wob   + (size_t)HID * HID;
  u16* Qr    = qkv   + (size_t)MROWS * QKV_N;
  u16* Kr    = Qr    + (size_t)BB * NHEADS * S_LEN * HDIM;
  u16* Vt    = Kr    + (size_t)BB * NKVH * S_LEN * HDIM;
  u16* attn  = Vt    + (size_t)BB * NKVH * S_LEN * HDIM;
  float* cs  = (float*)(attn + (size_t)MROWS * HID);

  k_prep<<<dim3(PB_CS), 256, 0, stream>>>(x, Wq, Wk, Wv, Wo, xb, Wqkvb, Wob, cs);
  k_gemm_bt<1><<<dim3(QKV_N / 128, MROWS / 128), 256, 0, stream>>>(xb, Wqkvb, qkv, MROWS, QKV_N, HID);
  k_ropev<<<dim3(BB * 256), 256, 0, stream>>>(qkv, cs, Qr, Kr, Vt);
  k_attn<<<dim3(BB * NHEADS, 16), 256, 0, stream>>>(Qr, Kr, Vt, attn);
  k_gemm_bt<0><<<dim3(HID / 128, MROWS / 128), 256, 0, stream>>>(attn, Wob, out, MROWS, HID, HID);
}

// Round 6
// 231.498 us; speedup vs baseline: 1.6811x; 1.0167x over previous
//
#include <hip/hip_runtime.h>

typedef unsigned short u16;
typedef __bf16 bf16x8 __attribute__((ext_vector_type(8)));
typedef float f32x4 __attribute__((ext_vector_type(4)));
typedef short s16x4 __attribute__((ext_vector_type(4)));

#define S_LEN  2048
#define NHEADS 16
#define NKVH   4
#define HDIM   128
#define BB     2
#define MROWS  4096   // B*S
#define QKV_N  3072   // NH*HD + 2*NKV*HD
#define HID    2048

__device__ __forceinline__ u16 f2b(float f) {
  union { float f; unsigned u; } x; x.f = f;
  unsigned r = x.u + 0x7fffu + ((x.u >> 16) & 1u);
  return (u16)(r >> 16);
}
__device__ __forceinline__ float b2f(u16 v) {
  union { unsigned u; float f; } x; x.u = ((unsigned)v) << 16;
  return x.f;
}
__device__ __forceinline__ void gload_lds16(const u16* g, u16* l) {
  __builtin_amdgcn_global_load_lds((__attribute__((address_space(1))) void*)g,
                                   (__attribute__((address_space(3))) void*)l,
                                   16, 0, 0);
}
__device__ __forceinline__ unsigned cvtpk(float lo, float hi) {
  unsigned r;
  asm("v_cvt_pk_bf16_f32 %0, %1, %2" : "=v"(r) : "v"(lo), "v"(hi));
  return r;
}
#if __has_builtin(__builtin_amdgcn_mfma_f32_16x16x16bf16_1k)
__device__ __forceinline__ f32x4 mfma16(s16x4 a, s16x4 b, f32x4 c) {
  return __builtin_amdgcn_mfma_f32_16x16x16bf16_1k(a, b, c, 0, 0, 0);
}
#else
__device__ __forceinline__ f32x4 mfma16(s16x4 a, s16x4 b, f32x4 c) {
  f32x4 d;
  asm volatile("v_mfma_f32_16x16x16_bf16 %0, %1, %2, %3"
               : "=v"(d) : "v"(a), "v"(b), "v"(c));
  return d;
}
#endif

// ---- one-launch prep: all fp32->bf16 converts + RoPE cos/sin table ----
#define PB_X   8192
#define PB_WQ  (PB_X + 4096)
#define PB_WK  (PB_WQ + 1024)
#define PB_WV  (PB_WK + 1024)
#define PB_WO  (PB_WV + 4096)
#define PB_CS  (PB_WO + 512)
__global__ void k_prep(const float* __restrict__ x,
                       const float* __restrict__ Wq, const float* __restrict__ Wk,
                       const float* __restrict__ Wv, const float* __restrict__ Wo,
                       u16* __restrict__ xb, u16* __restrict__ Wqkvb,
                       u16* __restrict__ Wob, float* __restrict__ cs)
{
  const int bid = blockIdx.x, tid = threadIdx.x;
  const float* src; u16* dst; int i;
  if (bid < PB_X)       { i = bid * 256 + tid;            src = x;  dst = xb; }
  else if (bid < PB_WQ) { i = (bid - PB_X) * 256 + tid;   src = Wq; dst = Wqkvb; }
  else if (bid < PB_WK) { i = (bid - PB_WQ) * 256 + tid;  src = Wk; dst = Wqkvb + (size_t)2048 * HID; }
  else if (bid < PB_WV) { i = (bid - PB_WK) * 256 + tid;  src = Wv; dst = Wqkvb + (size_t)2560 * HID; }
  else if (bid < PB_WO) { i = (bid - PB_WV) * 256 + tid;  src = Wo; dst = Wob; }
  else {
    const int p = (bid - PB_WO) * 256 + tid;
    const int s = p >> 6, j = p & 63;
    float inv = expf(-(float)j * 0.14391156831212787f);
    float ang = (float)s * inv;
    float c, sn; sincosf(ang, &sn, &c);
    cs[p * 2 + 0] = c; cs[p * 2 + 1] = sn;
    return;
  }
  float4 v = ((const float4*)src)[i];
  ushort4 o;
  o.x = f2b(v.x); o.y = f2b(v.y); o.z = f2b(v.z); o.w = f2b(v.w);
  ((ushort4*)dst)[i] = o;
}

// C[M][N] = A[M][K] * B[N][K]^T, bf16 in, bf16 or fp32 out. 128x128 tile, BK=32.
template <int OUT_BF16>
__global__ __launch_bounds__(256) void k_gemm_bt(
    const u16* __restrict__ A, const u16* __restrict__ Bm, void* __restrict__ Cv,
    int M, int N, int K)
{
  __shared__ u16 Al[128 * 32];
  __shared__ u16 Bl[128 * 32];
  const int tid = threadIdx.x;
  const int wave = tid >> 6, lane = tid & 63;
  const int l15 = lane & 15, l4 = lane >> 4;
  const int wr = wave >> 1, wc = wave & 1;
  const int row0 = blockIdx.y * 128, col0 = blockIdx.x * 128;

  f32x4 zero = {0.f, 0.f, 0.f, 0.f};
  f32x4 acc[4][4];
#pragma unroll
  for (int m = 0; m < 4; ++m)
#pragma unroll
    for (int n = 0; n < 4; ++n) acc[m][n] = zero;

  const int e0 = lane * 8;
  for (int kb = 0; kb < K; kb += 32) {
#pragma unroll
    for (int it = 0; it < 2; ++it) {
      const int chunk = it * 4 + wave;
      const int e = chunk * 512 + e0;
      const int r = e >> 5, c = e & 31;
      gload_lds16(A + (size_t)(row0 + r) * K + kb + c, Al + chunk * 512);
      gload_lds16(Bm + (size_t)(col0 + r) * K + kb + c, Bl + chunk * 512);
    }
    __syncthreads();
    bf16x8 af[4], bfv[4];
#pragma unroll
    for (int m = 0; m < 4; ++m)
      af[m] = *(const bf16x8*)(Al + (wr * 64 + m * 16 + l15) * 32 + l4 * 8);
#pragma unroll
    for (int n = 0; n < 4; ++n)
      bfv[n] = *(const bf16x8*)(Bl + (wc * 64 + n * 16 + l15) * 32 + l4 * 8);
#pragma unroll
    for (int m = 0; m < 4; ++m)
#pragma unroll
      for (int n = 0; n < 4; ++n)
        acc[m][n] = __builtin_amdgcn_mfma_f32_16x16x32_bf16(af[m], bfv[n], acc[m][n], 0, 0, 0);
    __syncthreads();
  }
#pragma unroll
  for (int m = 0; m < 4; ++m) {
    const int r = row0 + wr * 64 + m * 16 + l4 * 4;
#pragma unroll
    for (int n = 0; n < 4; ++n) {
      const int c = col0 + wc * 64 + n * 16 + l15;
#pragma unroll
      for (int j = 0; j < 4; ++j) {
        const float v = acc[m][n][j];
        if (OUT_BF16) ((u16*)Cv)[(size_t)(r + j) * N + c] = f2b(v);
        else          ((float*)Cv)[(size_t)(r + j) * N + c] = v;
      }
    }
  }
}

// ---- fused RoPE (Q pre-scaled by softmax scale * log2e) + K RoPE + V transpose ----
__global__ __launch_bounds__(256) void k_ropev(
    const u16* __restrict__ qkv, const float* __restrict__ cs,
    u16* __restrict__ Qr, u16* __restrict__ Kr, u16* __restrict__ Vt)
{
  const int blk = blockIdx.x;            // b*256 + (s>>3)
  const int b = blk >> 8, s0 = (blk & 255) << 3;
  const int tid = threadIdx.x;
  const float S2 = 0.08838834764831845f * 1.4426950408889634f;
#pragma unroll
  for (int p = tid; p < 8192; p += 256) {
    const int s = p >> 10, rem = p & 1023, h = rem >> 6, j = rem & 63;
    const int sg = s0 + s;
    const float c = cs[(sg * 64 + j) * 2], sn = cs[(sg * 64 + j) * 2 + 1];
    const u16* src = qkv + (size_t)(b * S_LEN + sg) * QKV_N + h * 128;
    const float x0 = b2f(src[j]), x1 = b2f(src[64 + j]);
    const size_t base = ((size_t)(b * NHEADS + h) * S_LEN + sg) * HDIM;
    Qr[base + j]      = f2b((x0 * c - x1 * sn) * S2);
    Qr[base + 64 + j] = f2b((x1 * c + x0 * sn) * S2);
  }
#pragma unroll
  for (int p = tid; p < 2048; p += 256) {
    const int s = p >> 8, rem = p & 255, h = rem >> 6, j = rem & 63;
    const int sg = s0 + s;
    const float c = cs[(sg * 64 + j) * 2], sn = cs[(sg * 64 + j) * 2 + 1];
    const u16* src = qkv + (size_t)(b * S_LEN + sg) * QKV_N + 2048 + h * 128;
    const float x0 = b2f(src[j]), x1 = b2f(src[64 + j]);
    const size_t base = ((size_t)(b * NKVH + h) * S_LEN + sg) * HDIM;
    Kr[base + j]      = f2b(x0 * c - x1 * sn);
    Kr[base + 64 + j] = f2b(x1 * c + x0 * sn);
  }
#pragma unroll
  for (int vi = 0; vi < 2; ++vi) {
    const int idx = vi * 256 + tid, h = idx >> 7, d = idx & 127;
    union { u16 u[8]; uint4 v; } bb;
#pragma unroll
    for (int s = 0; s < 8; ++s)
      bb.u[s] = qkv[(size_t)(b * S_LEN + s0 + s) * QKV_N + 2560 + idx];
    *(uint4*)(Vt + ((size_t)(b * NKVH + h) * HDIM + d) * S_LEN + s0) = bb.v;
  }
}

// ---- flash attention v6: swapped QK^T, in-register P (no P LDS),
// ---- PV via 16x16x16 MFMA from registers, scalar per-lane softmax state ----
__device__ __forceinline__ void attn_qtile(
    int qt, int lastPhase,
    const u16* __restrict__ Q, const u16* __restrict__ Kg, const u16* __restrict__ Vg,
    u16* __restrict__ Out, int bh,
    u16* Kl0, u16* Kl1, u16* Vl0, u16* Vl1,
    const int (&ko)[4], const int (&vo)[4],
    int wave, int lane, int& cur)
{
  const int l15 = lane & 15, l4 = lane >> 4;
  const int b = bh >> 4, h = bh & 15;
  const int qw0 = qt * 64 + wave * 16;
  const u16* Qg = Q + ((size_t)bh * S_LEN + qw0) * HDIM;

  bf16x8 qf[4];
#pragma unroll
  for (int kc = 0; kc < 4; ++kc)
    qf[kc] = *(const bf16x8*)(Qg + l15 * HDIM + kc * 32 + l4 * 8);

  f32x4 zero = {0.f, 0.f, 0.f, 0.f};
  f32x4 oacc[8];
#pragma unroll
  for (int i = 0; i < 8; ++i) oacc[i] = zero;
  float m_r = -1e30f, l_p = 0.f;   // per-lane: full row state for q = qw0 + l15

  const int nt = qt + 1;
  const int qg = qw0 + l15;

  for (int t = 0; t < nt; ++t) {
    const int kt = t * 64;
    u16* Vb = cur ? Vl1 : Vl0;
#pragma unroll
    for (int it = 0; it < 4; ++it)
      gload_lds16(Vg + (size_t)vo[it] + kt, Vb + (it * 4 + wave) * 512);
    const int hasNext = (t + 1 < nt) || (!lastPhase);
    const int ktn = (t + 1 < nt) ? kt + 64 : 0;
    u16* Kn = cur ? Kl0 : Kl1;
    if (hasNext) {
#pragma unroll
      for (int it = 0; it < 4; ++it)
        gload_lds16(Kg + (size_t)ktn * HDIM + ko[it], Kn + (it * 4 + wave) * 512);
      asm volatile("s_waitcnt vmcnt(8)" ::: "memory");
    } else {
      asm volatile("s_waitcnt vmcnt(4)" ::: "memory");
    }
    __builtin_amdgcn_sched_barrier(0);
    __builtin_amdgcn_s_barrier();
    __builtin_amdgcn_sched_barrier(0);

    const char* Kb = (const char*)(cur ? Kl1 : Kl0);
    // ---- S^T = K Q^T : lane owns q=l15, k = 16n + 4*l4 + j ----
    f32x4 s[4];
#pragma unroll
    for (int n = 0; n < 4; ++n) s[n] = zero;
    __builtin_amdgcn_s_setprio(1);
#pragma unroll
    for (int n = 0; n < 4; ++n) {
      const int row = n * 16 + l15;
#pragma unroll
      for (int kc = 0; kc < 4; ++kc) {
        const int ab = (row * 256 + kc * 64 + l4 * 16) ^ ((row & 7) << 4);
        bf16x8 kf = *(const bf16x8*)(Kb + ab);
        s[n] = __builtin_amdgcn_mfma_f32_16x16x32_bf16(kf, qf[kc], s[n], 0, 0, 0);
      }
    }
    __builtin_amdgcn_s_setprio(0);
    // ---- (rare) causal mask + per-lane max over owned k ----
    float sv[4][4];
    if (kt + 63 > qw0) {
#pragma unroll
      for (int n = 0; n < 4; ++n)
#pragma unroll
        for (int j = 0; j < 4; ++j) {
          float x = s[n][j];
          if (kt + n * 16 + l4 * 4 + j > qg) x = -1e30f;
          sv[n][j] = x;
        }
    } else {
#pragma unroll
      for (int n = 0; n < 4; ++n)
#pragma unroll
        for (int j = 0; j < 4; ++j) sv[n][j] = s[n][j];
    }
    float pm = sv[0][0];
#pragma unroll
    for (int n = 0; n < 4; ++n)
#pragma unroll
      for (int j = 0; j < 4; ++j) pm = fmaxf(pm, sv[n][j]);
    // ---- defer-max: rescale only when the lane's partial max jumps ----
    if (!__all(pm <= m_r + 11.5416f)) {
      float pf = fmaxf(pm, __shfl_xor(pm, 16, 64));
      pf = fmaxf(pf, __shfl_xor(pf, 32, 64));          // full row max (quad)
      const float mn = fmaxf(m_r, pf);
      const float sc = exp2f(m_r - mn);
      m_r = mn;
      l_p *= sc;
      float scq[4];
#pragma unroll
      for (int j = 0; j < 4; ++j) scq[j] = __shfl(sc, l4 * 4 + j, 64);
#pragma unroll
      for (int nd = 0; nd < 8; ++nd)
#pragma unroll
        for (int j = 0; j < 4; ++j) oacc[nd][j] *= scq[j];
    }
    // ---- P = exp2(sv - m), pack to bf16 pairs in-register (A-frags) ----
    union { unsigned u[2]; s16x4 v; } a[4];
#pragma unroll
    for (int n = 0; n < 4; ++n) {
      const float p0 = exp2f(sv[n][0] - m_r);
      const float p1 = exp2f(sv[n][1] - m_r);
      const float p2 = exp2f(sv[n][2] - m_r);
      const float p3 = exp2f(sv[n][3] - m_r);
      l_p += (p0 + p1) + (p2 + p3);
      a[n].u[0] = cvtpk(p0, p1);
      a[n].u[1] = cvtpk(p2, p3);
    }
    // ---- V(t) ready ----
    if (hasNext) asm volatile("s_waitcnt vmcnt(4)" ::: "memory");
    else         asm volatile("s_waitcnt vmcnt(0)" ::: "memory");
    __builtin_amdgcn_sched_barrier(0);
    __builtin_amdgcn_s_barrier();
    __builtin_amdgcn_sched_barrier(0);
    // ---- O += P V : 16x16x16 MFMA, A direct from registers ----
    __builtin_amdgcn_s_setprio(1);
#pragma unroll
    for (int nd = 0; nd < 8; ++nd) {
      const int d = nd * 16 + l15;
      const int rowb = d * 128, swz = (d & 7) << 4;
#pragma unroll
      for (int n = 0; n < 4; ++n) {
        const int ab = (rowb + n * 32 + l4 * 8) ^ swz;
        s16x4 vf = *(const s16x4*)((const char*)Vb + ab);
        oacc[nd] = mfma16(a[n].v, vf, oacc[nd]);
      }
    }
    __builtin_amdgcn_s_setprio(0);
    cur ^= 1;
  }

  // ---- epilogue: finish l reduction, fetch per-row l, normalize, store ----
  l_p += __shfl_xor(l_p, 16, 64);
  l_p += __shfl_xor(l_p, 32, 64);
  float il[4];
#pragma unroll
  for (int j = 0; j < 4; ++j) il[j] = 1.f / __shfl(l_p, l4 * 4 + j, 64);
  const size_t obase = ((size_t)b * S_LEN + qw0 + l4 * 4) * HID + h * HDIM;
#pragma unroll
  for (int nd = 0; nd < 8; ++nd)
#pragma unroll
    for (int j = 0; j < 4; ++j)
      Out[obase + (size_t)j * HID + nd * 16 + l15] = f2b(oacc[nd][j] * il[j]);
}

__global__ __launch_bounds__(256) void k_attn(
    const u16* __restrict__ Q, const u16* __restrict__ Kr,
    const u16* __restrict__ Vt, u16* __restrict__ Out)
{
  __shared__ u16 Kl[2][64 * 128];   // 32 KB dbuf, XOR ^((kv&7)<<4)
  __shared__ u16 Vl[2][128 * 64];   // 32 KB dbuf, XOR ^((d&7)<<4)
  const int tid = threadIdx.x;
  const int wave = tid >> 6, lane = tid & 63;
  const int bh = blockIdx.x;              // XCD = bh%8: KV L2 locality
  const int pairi = blockIdx.y;           // pair (31-pairi, pairi): 33 tiles/block
  const int b = bh >> 4, h = bh & 15;
  const int kvh = h >> 2;

  const u16* Kg = Kr + (size_t)(b * NKVH + kvh) * S_LEN * HDIM;
  const u16* Vg = Vt + (size_t)(b * NKVH + kvh) * HDIM * S_LEN;

  int ko[4], vo[4];
#pragma unroll
  for (int it = 0; it < 4; ++it) {
    const int c = it * 4 + wave;
    const int L = c * 1024 + lane * 16;
    const int r = L >> 8;  const int w2 = (L & 255) ^ ((r & 7) << 4);
    ko[it] = r * HDIM + (w2 >> 1);
    const int d = L >> 7;  const int wv = (L & 127) ^ ((d & 7) << 4);
    vo[it] = d * S_LEN + (wv >> 1);
  }
#pragma unroll
  for (int it = 0; it < 4; ++it)
    gload_lds16(Kg + ko[it], &Kl[0][(it * 4 + wave) * 512]);

  int cur = 0;
  attn_qtile(31 - pairi, 0, Q, Kg, Vg, Out, bh, &Kl[0][0], &Kl[1][0],
             &Vl[0][0], &Vl[1][0], ko, vo, wave, lane, cur);
  attn_qtile(pairi,      1, Q, Kg, Vg, Out, bh, &Kl[0][0], &Kl[1][0],
             &Vl[0][0], &Vl[1][0], ko, vo, wave, lane, cur);
}

extern "C" void kernel_launch(void* const* d_in, const int* in_sizes, int n_in,
                              void* d_out, int out_size, void* d_ws, size_t ws_size,
                              hipStream_t stream)
{
  const float* x  = (const float*)d_in[0];
  const float* Wq = (const float*)d_in[2];
  const float* Wk = (const float*)d_in[3];
  const float* Wv = (const float*)d_in[4];
  const float* Wo = (const float*)d_in[5];
  float* out = (float*)d_out;

  u16* xb    = (u16*)d_ws;
  u16* Wqkvb = xb    + (size_t)MROWS * HID;
  u16* Wob   = Wqkvb + (size_t)QKV_N * HID;
  u16* qkv   = Wob   + (size_t)HID * HID;
  u16* Qr    = qkv   + (size_t)MROWS * QKV_N;
  u16* Kr    = Qr    + (size_t)BB * NHEADS * S_LEN * HDIM;
  u16* Vt    = Kr    + (size_t)BB * NKVH * S_LEN * HDIM;
  u16* attn  = Vt    + (size_t)BB * NKVH * S_LEN * HDIM;
  float* cs  = (float*)(attn + (size_t)MROWS * HID);

  k_prep<<<dim3(PB_CS), 256, 0, stream>>>(x, Wq, Wk, Wv, Wo, xb, Wqkvb, Wob, cs);
  k_gemm_bt<1><<<dim3(QKV_N / 128, MROWS / 128), 256, 0, stream>>>(xb, Wqkvb, qkv, MROWS, QKV_N, HID);
  k_ropev<<<dim3(BB * 256), 256, 0, stream>>>(qkv, cs, Qr, Kr, Vt);
  k_attn<<<dim3(BB * NHEADS, 16), 256, 0, stream>>>(Qr, Kr, Vt, attn);
  k_gemm_bt<0><<<dim3(HID / 128, MROWS / 128), 256, 0, stream>>>(attn, Wob, out, MROWS, HID, HID);
}

// Round 7
// 222.664 us; speedup vs baseline: 1.7478x; 1.0397x over previous
//
#include <hip/hip_runtime.h>

typedef unsigned short u16;
typedef __bf16 bf16x8 __attribute__((ext_vector_type(8)));
typedef float f32x4 __attribute__((ext_vector_type(4)));
typedef short s16x4 __attribute__((ext_vector_type(4)));

#define S_LEN  2048
#define NHEADS 16
#define NKVH   4
#define HDIM   128
#define BB     2
#define MROWS  4096   // B*S
#define QKV_N  3072   // NH*HD + 2*NKV*HD
#define HID    2048

__device__ __forceinline__ u16 f2b(float f) {
  union { float f; unsigned u; } x; x.f = f;
  unsigned r = x.u + 0x7fffu + ((x.u >> 16) & 1u);
  return (u16)(r >> 16);
}
__device__ __forceinline__ float b2f(u16 v) {
  union { unsigned u; float f; } x; x.u = ((unsigned)v) << 16;
  return x.f;
}
__device__ __forceinline__ void gload_lds16(const u16* g, u16* l) {
  __builtin_amdgcn_global_load_lds((__attribute__((address_space(1))) void*)g,
                                   (__attribute__((address_space(3))) void*)l,
                                   16, 0, 0);
}
__device__ __forceinline__ unsigned cvtpk(float lo, float hi) {
  unsigned r;
  asm("v_cvt_pk_bf16_f32 %0, %1, %2" : "=v"(r) : "v"(lo), "v"(hi));
  return r;
}
#if __has_builtin(__builtin_amdgcn_mfma_f32_16x16x16bf16_1k)
__device__ __forceinline__ f32x4 mfma16(s16x4 a, s16x4 b, f32x4 c) {
  return __builtin_amdgcn_mfma_f32_16x16x16bf16_1k(a, b, c, 0, 0, 0);
}
#else
__device__ __forceinline__ f32x4 mfma16(s16x4 a, s16x4 b, f32x4 c) {
  f32x4 d;
  asm volatile("v_mfma_f32_16x16x16_bf16 %0, %1, %2, %3"
               : "=v"(d) : "v"(a), "v"(b), "v"(c));
  return d;
}
#endif

#define SBAR() do { __builtin_amdgcn_sched_barrier(0); \
                    __builtin_amdgcn_s_barrier();      \
                    __builtin_amdgcn_sched_barrier(0); } while (0)

// ---- one-launch prep: all fp32->bf16 converts + RoPE cos/sin table ----
#define PB_X   8192
#define PB_WQ  (PB_X + 4096)
#define PB_WK  (PB_WQ + 1024)
#define PB_WV  (PB_WK + 1024)
#define PB_WO  (PB_WV + 4096)
#define PB_CS  (PB_WO + 512)
__global__ void k_prep(const float* __restrict__ x,
                       const float* __restrict__ Wq, const float* __restrict__ Wk,
                       const float* __restrict__ Wv, const float* __restrict__ Wo,
                       u16* __restrict__ xb, u16* __restrict__ Wqkvb,
                       u16* __restrict__ Wob, float* __restrict__ cs)
{
  const int bid = blockIdx.x, tid = threadIdx.x;
  const float* src; u16* dst; int i;
  if (bid < PB_X)       { i = bid * 256 + tid;            src = x;  dst = xb; }
  else if (bid < PB_WQ) { i = (bid - PB_X) * 256 + tid;   src = Wq; dst = Wqkvb; }
  else if (bid < PB_WK) { i = (bid - PB_WQ) * 256 + tid;  src = Wk; dst = Wqkvb + (size_t)2048 * HID; }
  else if (bid < PB_WV) { i = (bid - PB_WK) * 256 + tid;  src = Wv; dst = Wqkvb + (size_t)2560 * HID; }
  else if (bid < PB_WO) { i = (bid - PB_WV) * 256 + tid;  src = Wo; dst = Wob; }
  else {
    const int p = (bid - PB_WO) * 256 + tid;
    const int s = p >> 6, j = p & 63;
    float inv = expf(-(float)j * 0.14391156831212787f);
    float ang = (float)s * inv;
    float c, sn; sincosf(ang, &sn, &c);
    cs[p * 2 + 0] = c; cs[p * 2 + 1] = sn;
    return;
  }
  float4 v = ((const float4*)src)[i];
  ushort4 o;
  o.x = f2b(v.x); o.y = f2b(v.y); o.z = f2b(v.z); o.w = f2b(v.w);
  ((ushort4*)dst)[i] = o;
}

// ======================================================================
// 8-phase 256x256 GEMM (T2 swizzle + T3/T4 counted-vmcnt + T5 setprio)
// C[M][N] = A[M][K] * B[N][K]^T. 512 thr = 8 waves (2M x 4N), BK=64.
// LDS: A,B each [2 buf][2 half][128 rows][64 k] in 16x32 subtiles
// (1024 B, st_16x32 swizzle: off ^= ((off>>9)&1)<<5).
// ======================================================================
#define MFMA_GRP(AV, BV, MO, NO)                                              \
  __builtin_amdgcn_s_setprio(1);                                              \
  _Pragma("unroll") for (int kk = 0; kk < 2; ++kk)                            \
  _Pragma("unroll") for (int mm = 0; mm < 4; ++mm)                            \
  _Pragma("unroll") for (int nn = 0; nn < 2; ++nn)                            \
    acc[(MO) + mm][(NO) + nn] = __builtin_amdgcn_mfma_f32_16x16x32_bf16(      \
        AV[kk][mm], BV[kk][nn], acc[(MO) + mm][(NO) + nn], 0, 0, 0);          \
  __builtin_amdgcn_s_setprio(0);

template <int OUT_BF16>
__global__ __launch_bounds__(512, 2) void k_gemm256(
    const u16* __restrict__ A, const u16* __restrict__ Bm, void* __restrict__ Cv,
    int M, int N, int K)
{
  __shared__ u16 AL[2][2][8192];   // 64 KB
  __shared__ u16 BL[2][2][8192];   // 64 KB
  const int tid = threadIdx.x;
  const int wave = tid >> 6, lane = tid & 63;
  const int l15 = lane & 15, l4 = lane >> 4;
  const int wr = wave >> 2, wc = wave & 3;      // 2 M-waves x 4 N-waves
  // bijective XCD swizzle (nwg % 8 == 0 for all our grids)
  const int gx = gridDim.x;
  const int nwg = gx * gridDim.y;
  int bid = blockIdx.y * gx + blockIdx.x;
  bid = (bid & 7) * (nwg >> 3) + (bid >> 3);
  const int col0 = (bid % gx) * 256, row0 = (bid / gx) * 256;

  // per-thread staging: linear LDS dest (lane*16), pre-swizzled global source
  int srcOff[2], dstD[2];
#pragma unroll
  for (int li = 0; li < 2; ++li) {
    const int D = (li * 512 + tid) * 16;           // byte in 16 KB half
    const int off_p = D & 1023, si = D >> 10;
    const int off_l = off_p ^ (((off_p >> 9) & 1) << 5);
    const int R = si >> 1, C = si & 1;
    const int row = R * 16 + (off_l >> 6);
    const int colb = C * 64 + (off_l & 63);
    srcOff[li] = row * K + (colb >> 1);
    dstD[li] = D;
  }
  // ds_read lane offset inside a 1024-B subtile (swizzled)
  const int laneoff = (l15 * 64 + l4 * 16) ^ ((l15 >> 3) << 5);

  auto stage = [&](const u16* __restrict__ G, int grow0, int kb, u16* lds) {
#pragma unroll
    for (int li = 0; li < 2; ++li)
      gload_lds16(G + (size_t)grow0 * K + kb + srcOff[li],
                  (u16*)((char*)lds + dstD[li]));
  };

  f32x4 acc[8][4];
#pragma unroll
  for (int m = 0; m < 8; ++m)
#pragma unroll
    for (int n = 0; n < 4; ++n) acc[m][n] = f32x4{0.f, 0.f, 0.f, 0.f};

  const int nk = K >> 6;
  // prologue: tile0 (all 4 halves) + tile1 A halves; vmcnt(4) -> tile0 landed
  stage(A,  row0,       0,  &AL[0][0][0]);
  stage(A,  row0 + 128, 0,  &AL[0][1][0]);
  stage(Bm, col0,       0,  &BL[0][0][0]);
  stage(Bm, col0 + 128, 0,  &BL[0][1][0]);
  stage(A,  row0,       64, &AL[1][0][0]);
  stage(A,  row0 + 128, 64, &AL[1][1][0]);
  asm volatile("s_waitcnt vmcnt(4)" ::: "memory");
  SBAR();

  for (int t = 0; t < nk; ++t) {
    const int bi = t & 1;
    const bool sB = (t + 1 < nk);   // stage B halves of tile t+1
    const bool sA = (t + 2 < nk);   // stage A halves of tile t+2
    const char* Ab = (const char*)&AL[bi][wr][0];
    const char* Bb = (const char*)&BL[bi][wc >> 1][0] + (wc & 1) * 8192;
    bf16x8 a0[2][4], a1[2][4], b0[2][2], b1[2][2];
    // ---- P1: read A m0-3 + B n0-1; stage B-h0(t+1) ----
#pragma unroll
    for (int kk = 0; kk < 2; ++kk)
#pragma unroll
      for (int m = 0; m < 4; ++m)
        a0[kk][m] = *(const bf16x8*)(Ab + m * 2048 + kk * 1024 + laneoff);
#pragma unroll
    for (int kk = 0; kk < 2; ++kk)
#pragma unroll
      for (int n = 0; n < 2; ++n)
        b0[kk][n] = *(const bf16x8*)(Bb + n * 2048 + kk * 1024 + laneoff);
    if (sB) stage(Bm, col0, (t + 1) * 64, &BL[bi ^ 1][0][0]);
    SBAR();
    MFMA_GRP(a0, b0, 0, 0);
    SBAR();
    // ---- P2: read A m4-7; stage B-h1(t+1) ----
#pragma unroll
    for (int kk = 0; kk < 2; ++kk)
#pragma unroll
      for (int m = 0; m < 4; ++m)
        a1[kk][m] = *(const bf16x8*)(Ab + (m + 4) * 2048 + kk * 1024 + laneoff);
    if (sB) stage(Bm, col0 + 128, (t + 1) * 64, &BL[bi ^ 1][1][0]);
    SBAR();
    MFMA_GRP(a1, b0, 4, 0);
    SBAR();
    // ---- P3: read B n2-3; stage A-h0(t+2) into current buf ----
#pragma unroll
    for (int kk = 0; kk < 2; ++kk)
#pragma unroll
      for (int n = 0; n < 2; ++n)
        b1[kk][n] = *(const bf16x8*)(Bb + (n + 2) * 2048 + kk * 1024 + laneoff);
    if (sA) stage(A, row0, (t + 2) * 64, &AL[bi][0][0]);
    SBAR();
    MFMA_GRP(a1, b1, 4, 2);
    SBAR();
    // ---- P4: reg-only MFMA; stage A-h1(t+2); counted vmcnt ----
    if (sA) {
      stage(A, row0 + 128, (t + 2) * 64, &AL[bi][1][0]);
      asm volatile("s_waitcnt vmcnt(4)" ::: "memory");   // tile t+1 landed
    } else if (sB) {
      asm volatile("s_waitcnt vmcnt(0)" ::: "memory");   // tail drain
    }
    SBAR();
    MFMA_GRP(a0, b1, 0, 2);
    SBAR();
  }

  // ---- epilogue ----
#pragma unroll
  for (int m = 0; m < 8; ++m) {
    const int r = row0 + wr * 128 + m * 16 + l4 * 4;
#pragma unroll
    for (int n = 0; n < 4; ++n) {
      const int c = col0 + wc * 64 + n * 16 + l15;
#pragma unroll
      for (int j = 0; j < 4; ++j) {
        const float v = acc[m][n][j];
        if (OUT_BF16) ((u16*)Cv)[(size_t)(r + j) * N + c] = f2b(v);
        else          ((float*)Cv)[(size_t)(r + j) * N + c] = v;
      }
    }
  }
}

// C[M][N] = A[M][K] * B[N][K]^T, 128x128 tile, BK=32 (kept for out-proj).
template <int OUT_BF16>
__global__ __launch_bounds__(256) void k_gemm_bt(
    const u16* __restrict__ A, const u16* __restrict__ Bm, void* __restrict__ Cv,
    int M, int N, int K)
{
  __shared__ u16 Al[128 * 32];
  __shared__ u16 Bl[128 * 32];
  const int tid = threadIdx.x;
  const int wave = tid >> 6, lane = tid & 63;
  const int l15 = lane & 15, l4 = lane >> 4;
  const int wr = wave >> 1, wc = wave & 1;
  const int row0 = blockIdx.y * 128, col0 = blockIdx.x * 128;

  f32x4 zero = {0.f, 0.f, 0.f, 0.f};
  f32x4 acc[4][4];
#pragma unroll
  for (int m = 0; m < 4; ++m)
#pragma unroll
    for (int n = 0; n < 4; ++n) acc[m][n] = zero;

  const int e0 = lane * 8;
  for (int kb = 0; kb < K; kb += 32) {
#pragma unroll
    for (int it = 0; it < 2; ++it) {
      const int chunk = it * 4 + wave;
      const int e = chunk * 512 + e0;
      const int r = e >> 5, c = e & 31;
      gload_lds16(A + (size_t)(row0 + r) * K + kb + c, Al + chunk * 512);
      gload_lds16(Bm + (size_t)(col0 + r) * K + kb + c, Bl + chunk * 512);
    }
    __syncthreads();
    bf16x8 af[4], bfv[4];
#pragma unroll
    for (int m = 0; m < 4; ++m)
      af[m] = *(const bf16x8*)(Al + (wr * 64 + m * 16 + l15) * 32 + l4 * 8);
#pragma unroll
    for (int n = 0; n < 4; ++n)
      bfv[n] = *(const bf16x8*)(Bl + (wc * 64 + n * 16 + l15) * 32 + l4 * 8);
#pragma unroll
    for (int m = 0; m < 4; ++m)
#pragma unroll
      for (int n = 0; n < 4; ++n)
        acc[m][n] = __builtin_amdgcn_mfma_f32_16x16x32_bf16(af[m], bfv[n], acc[m][n], 0, 0, 0);
    __syncthreads();
  }
#pragma unroll
  for (int m = 0; m < 4; ++m) {
    const int r = row0 + wr * 64 + m * 16 + l4 * 4;
#pragma unroll
    for (int n = 0; n < 4; ++n) {
      const int c = col0 + wc * 64 + n * 16 + l15;
#pragma unroll
      for (int j = 0; j < 4; ++j) {
        const float v = acc[m][n][j];
        if (OUT_BF16) ((u16*)Cv)[(size_t)(r + j) * N + c] = f2b(v);
        else          ((float*)Cv)[(size_t)(r + j) * N + c] = v;
      }
    }
  }
}

// ---- fused RoPE (Q pre-scaled by softmax scale * log2e) + K RoPE + V transpose ----
__global__ __launch_bounds__(256) void k_ropev(
    const u16* __restrict__ qkv, const float* __restrict__ cs,
    u16* __restrict__ Qr, u16* __restrict__ Kr, u16* __restrict__ Vt)
{
  const int blk = blockIdx.x;            // b*256 + (s>>3)
  const int b = blk >> 8, s0 = (blk & 255) << 3;
  const int tid = threadIdx.x;
  const float S2 = 0.08838834764831845f * 1.4426950408889634f;
#pragma unroll
  for (int p = tid; p < 8192; p += 256) {
    const int s = p >> 10, rem = p & 1023, h = rem >> 6, j = rem & 63;
    const int sg = s0 + s;
    const float c = cs[(sg * 64 + j) * 2], sn = cs[(sg * 64 + j) * 2 + 1];
    const u16* src = qkv + (size_t)(b * S_LEN + sg) * QKV_N + h * 128;
    const float x0 = b2f(src[j]), x1 = b2f(src[64 + j]);
    const size_t base = ((size_t)(b * NHEADS + h) * S_LEN + sg) * HDIM;
    Qr[base + j]      = f2b((x0 * c - x1 * sn) * S2);
    Qr[base + 64 + j] = f2b((x1 * c + x0 * sn) * S2);
  }
#pragma unroll
  for (int p = tid; p < 2048; p += 256) {
    const int s = p >> 8, rem = p & 255, h = rem >> 6, j = rem & 63;
    const int sg = s0 + s;
    const float c = cs[(sg * 64 + j) * 2], sn = cs[(sg * 64 + j) * 2 + 1];
    const u16* src = qkv + (size_t)(b * S_LEN + sg) * QKV_N + 2048 + h * 128;
    const float x0 = b2f(src[j]), x1 = b2f(src[64 + j]);
    const size_t base = ((size_t)(b * NKVH + h) * S_LEN + sg) * HDIM;
    Kr[base + j]      = f2b(x0 * c - x1 * sn);
    Kr[base + 64 + j] = f2b(x1 * c + x0 * sn);
  }
#pragma unroll
  for (int vi = 0; vi < 2; ++vi) {
    const int idx = vi * 256 + tid, h = idx >> 7, d = idx & 127;
    union { u16 u[8]; uint4 v; } bb;
#pragma unroll
    for (int s = 0; s < 8; ++s)
      bb.u[s] = qkv[(size_t)(b * S_LEN + s0 + s) * QKV_N + 2560 + idx];
    *(uint4*)(Vt + ((size_t)(b * NKVH + h) * HDIM + d) * S_LEN + s0) = bb.v;
  }
}

// ---- flash attention v6 (unchanged): swapped QK^T, in-register P ----
__device__ __forceinline__ void attn_qtile(
    int qt, int lastPhase,
    const u16* __restrict__ Q, const u16* __restrict__ Kg, const u16* __restrict__ Vg,
    u16* __restrict__ Out, int bh,
    u16* Kl0, u16* Kl1, u16* Vl0, u16* Vl1,
    const int (&ko)[4], const int (&vo)[4],
    int wave, int lane, int& cur)
{
  const int l15 = lane & 15, l4 = lane >> 4;
  const int b = bh >> 4, h = bh & 15;
  const int qw0 = qt * 64 + wave * 16;
  const u16* Qg = Q + ((size_t)bh * S_LEN + qw0) * HDIM;

  bf16x8 qf[4];
#pragma unroll
  for (int kc = 0; kc < 4; ++kc)
    qf[kc] = *(const bf16x8*)(Qg + l15 * HDIM + kc * 32 + l4 * 8);

  f32x4 zero = {0.f, 0.f, 0.f, 0.f};
  f32x4 oacc[8];
#pragma unroll
  for (int i = 0; i < 8; ++i) oacc[i] = zero;
  float m_r = -1e30f, l_p = 0.f;

  const int nt = qt + 1;
  const int qg = qw0 + l15;

  for (int t = 0; t < nt; ++t) {
    const int kt = t * 64;
    u16* Vb = cur ? Vl1 : Vl0;
#pragma unroll
    for (int it = 0; it < 4; ++it)
      gload_lds16(Vg + (size_t)vo[it] + kt, Vb + (it * 4 + wave) * 512);
    const int hasNext = (t + 1 < nt) || (!lastPhase);
    const int ktn = (t + 1 < nt) ? kt + 64 : 0;
    u16* Kn = cur ? Kl0 : Kl1;
    if (hasNext) {
#pragma unroll
      for (int it = 0; it < 4; ++it)
        gload_lds16(Kg + (size_t)ktn * HDIM + ko[it], Kn + (it * 4 + wave) * 512);
      asm volatile("s_waitcnt vmcnt(8)" ::: "memory");
    } else {
      asm volatile("s_waitcnt vmcnt(4)" ::: "memory");
    }
    SBAR();

    const char* Kb = (const char*)(cur ? Kl1 : Kl0);
    f32x4 s[4];
#pragma unroll
    for (int n = 0; n < 4; ++n) s[n] = zero;
    __builtin_amdgcn_s_setprio(1);
#pragma unroll
    for (int n = 0; n < 4; ++n) {
      const int row = n * 16 + l15;
#pragma unroll
      for (int kc = 0; kc < 4; ++kc) {
        const int ab = (row * 256 + kc * 64 + l4 * 16) ^ ((row & 7) << 4);
        bf16x8 kf = *(const bf16x8*)(Kb + ab);
        s[n] = __builtin_amdgcn_mfma_f32_16x16x32_bf16(kf, qf[kc], s[n], 0, 0, 0);
      }
    }
    __builtin_amdgcn_s_setprio(0);
    float sv[4][4];
    if (kt + 63 > qw0) {
#pragma unroll
      for (int n = 0; n < 4; ++n)
#pragma unroll
        for (int j = 0; j < 4; ++j) {
          float x = s[n][j];
          if (kt + n * 16 + l4 * 4 + j > qg) x = -1e30f;
          sv[n][j] = x;
        }
    } else {
#pragma unroll
      for (int n = 0; n < 4; ++n)
#pragma unroll
        for (int j = 0; j < 4; ++j) sv[n][j] = s[n][j];
    }
    float pm = sv[0][0];
#pragma unroll
    for (int n = 0; n < 4; ++n)
#pragma unroll
      for (int j = 0; j < 4; ++j) pm = fmaxf(pm, sv[n][j]);
    if (!__all(pm <= m_r + 11.5416f)) {
      float pf = fmaxf(pm, __shfl_xor(pm, 16, 64));
      pf = fmaxf(pf, __shfl_xor(pf, 32, 64));
      const float mn = fmaxf(m_r, pf);
      const float sc = exp2f(m_r - mn);
      m_r = mn;
      l_p *= sc;
      float scq[4];
#pragma unroll
      for (int j = 0; j < 4; ++j) scq[j] = __shfl(sc, l4 * 4 + j, 64);
#pragma unroll
      for (int nd = 0; nd < 8; ++nd)
#pragma unroll
        for (int j = 0; j < 4; ++j) oacc[nd][j] *= scq[j];
    }
    union { unsigned u[2]; s16x4 v; } a[4];
#pragma unroll
    for (int n = 0; n < 4; ++n) {
      const float p0 = exp2f(sv[n][0] - m_r);
      const float p1 = exp2f(sv[n][1] - m_r);
      const float p2 = exp2f(sv[n][2] - m_r);
      const float p3 = exp2f(sv[n][3] - m_r);
      l_p += (p0 + p1) + (p2 + p3);
      a[n].u[0] = cvtpk(p0, p1);
      a[n].u[1] = cvtpk(p2, p3);
    }
    if (hasNext) asm volatile("s_waitcnt vmcnt(4)" ::: "memory");
    else         asm volatile("s_waitcnt vmcnt(0)" ::: "memory");
    SBAR();
    __builtin_amdgcn_s_setprio(1);
#pragma unroll
    for (int nd = 0; nd < 8; ++nd) {
      const int d = nd * 16 + l15;
      const int rowb = d * 128, swz = (d & 7) << 4;
#pragma unroll
      for (int n = 0; n < 4; ++n) {
        const int ab = (rowb + n * 32 + l4 * 8) ^ swz;
        s16x4 vf = *(const s16x4*)((const char*)Vb + ab);
        oacc[nd] = mfma16(a[n].v, vf, oacc[nd]);
      }
    }
    __builtin_amdgcn_s_setprio(0);
    cur ^= 1;
  }

  l_p += __shfl_xor(l_p, 16, 64);
  l_p += __shfl_xor(l_p, 32, 64);
  float il[4];
#pragma unroll
  for (int j = 0; j < 4; ++j) il[j] = 1.f / __shfl(l_p, l4 * 4 + j, 64);
  const size_t obase = ((size_t)b * S_LEN + qw0 + l4 * 4) * HID + h * HDIM;
#pragma unroll
  for (int nd = 0; nd < 8; ++nd)
#pragma unroll
    for (int j = 0; j < 4; ++j)
      Out[obase + (size_t)j * HID + nd * 16 + l15] = f2b(oacc[nd][j] * il[j]);
}

__global__ __launch_bounds__(256) void k_attn(
    const u16* __restrict__ Q, const u16* __restrict__ Kr,
    const u16* __restrict__ Vt, u16* __restrict__ Out)
{
  __shared__ u16 Kl[2][64 * 128];
  __shared__ u16 Vl[2][128 * 64];
  const int tid = threadIdx.x;
  const int wave = tid >> 6, lane = tid & 63;
  const int bh = blockIdx.x;
  const int pairi = blockIdx.y;
  const int b = bh >> 4, h = bh & 15;
  const int kvh = h >> 2;

  const u16* Kg = Kr + (size_t)(b * NKVH + kvh) * S_LEN * HDIM;
  const u16* Vg = Vt + (size_t)(b * NKVH + kvh) * HDIM * S_LEN;

  int ko[4], vo[4];
#pragma unroll
  for (int it = 0; it < 4; ++it) {
    const int c = it * 4 + wave;
    const int L = c * 1024 + lane * 16;
    const int r = L >> 8;  const int w2 = (L & 255) ^ ((r & 7) << 4);
    ko[it] = r * HDIM + (w2 >> 1);
    const int d = L >> 7;  const int wv = (L & 127) ^ ((d & 7) << 4);
    vo[it] = d * S_LEN + (wv >> 1);
  }
#pragma unroll
  for (int it = 0; it < 4; ++it)
    gload_lds16(Kg + ko[it], &Kl[0][(it * 4 + wave) * 512]);

  int cur = 0;
  attn_qtile(31 - pairi, 0, Q, Kg, Vg, Out, bh, &Kl[0][0], &Kl[1][0],
             &Vl[0][0], &Vl[1][0], ko, vo, wave, lane, cur);
  attn_qtile(pairi,      1, Q, Kg, Vg, Out, bh, &Kl[0][0], &Kl[1][0],
             &Vl[0][0], &Vl[1][0], ko, vo, wave, lane, cur);
}

extern "C" void kernel_launch(void* const* d_in, const int* in_sizes, int n_in,
                              void* d_out, int out_size, void* d_ws, size_t ws_size,
                              hipStream_t stream)
{
  const float* x  = (const float*)d_in[0];
  const float* Wq = (const float*)d_in[2];
  const float* Wk = (const float*)d_in[3];
  const float* Wv = (const float*)d_in[4];
  const float* Wo = (const float*)d_in[5];
  float* out = (float*)d_out;

  u16* xb    = (u16*)d_ws;
  u16* Wqkvb = xb    + (size_t)MROWS * HID;
  u16* Wob   = Wqkvb + (size_t)QKV_N * HID;
  u16* qkv   = Wob   + (size_t)HID * HID;
  u16* Qr    = qkv   + (size_t)MROWS * QKV_N;
  u16* Kr    = Qr    + (size_t)BB * NHEADS * S_LEN * HDIM;
  u16* Vt    = Kr    + (size_t)BB * NKVH * S_LEN * HDIM;
  u16* attn  = Vt    + (size_t)BB * NKVH * S_LEN * HDIM;
  float* cs  = (float*)(attn + (size_t)MROWS * HID);

  k_prep<<<dim3(PB_CS), 256, 0, stream>>>(x, Wq, Wk, Wv, Wo, xb, Wqkvb, Wob, cs);
  k_gemm256<1><<<dim3(QKV_N / 256, MROWS / 256), 512, 0, stream>>>(xb, Wqkvb, qkv, MROWS, QKV_N, HID);
  k_ropev<<<dim3(BB * 256), 256, 0, stream>>>(qkv, cs, Qr, Kr, Vt);
  k_attn<<<dim3(BB * NHEADS, 16), 256, 0, stream>>>(Qr, Kr, Vt, attn);
  k_gemm_bt<0><<<dim3(HID / 128, MROWS / 128), 256, 0, stream>>>(attn, Wob, out, MROWS, HID, HID);
}